// Round 1
// baseline (643.540 us; speedup 1.0000x reference)
//
#include <hip/hip_runtime.h>

#define N_NODES 100000
#define N_EDGES 1600000
#define IN_DIM 128
#define HID_DIM 128
#define OUT_DIM 64

// ---------- helpers ----------
__device__ __forceinline__ int eidx(const void* ei, int is64, int i) {
  return is64 ? (int)((const long long*)ei)[i] : ((const int*)ei)[i];
}

// ---------- zero workspace region ----------
__global__ void zero_kernel(unsigned int* p, int n) {
  int i = blockIdx.x * blockDim.x + threadIdx.x;
  int stride = gridDim.x * blockDim.x;
  for (; i < n; i += stride) p[i] = 0u;
}

// ---------- detect int64 vs int32 edge_index ----------
// If int64: high (odd) 32-bit words are all zero (values in [0,1e5)).
// If int32: odd words are edge values; all-zero over 256 samples ~ impossible.
__global__ void detect_kernel(const unsigned int* ei, int* flag) {
  __shared__ int nz;
  if (threadIdx.x == 0) nz = 0;
  __syncthreads();
  unsigned int v = ei[1 + 2 * threadIdx.x];
  if (v != 0u) nz = 1;
  __syncthreads();
  if (threadIdx.x == 0) *flag = (nz == 0) ? 1 : 0;
}

// ---------- in-degree count over col ----------
__global__ void count_kernel(const void* ei, const int* flag, int* cnt) {
  int is64 = *flag;
  int i = blockIdx.x * blockDim.x + threadIdx.x;
  int stride = gridDim.x * blockDim.x;
  for (; i < N_EDGES; i += stride) {
    int c = eidx(ei, is64, N_EDGES + i);
    atomicAdd(&cnt[c], 1);
  }
}

// ---------- dinv = rsqrt(deg), deg = in-degree + self loop ----------
__global__ void dinv_kernel(const int* cnt, float* dinv) {
  int i = blockIdx.x * blockDim.x + threadIdx.x;
  if (i < N_NODES) dinv[i] = rsqrtf((float)(cnt[i] + 1));
}

// ---------- wacc[row] += dinv[col]  (layer-2 weight, mean pushed through) ----------
__global__ void wscatter_kernel(const void* ei, const int* flag,
                                const float* __restrict__ dinv, float* wacc) {
  int is64 = *flag;
  int i = blockIdx.x * blockDim.x + threadIdx.x;
  int stride = gridDim.x * blockDim.x;
  for (; i < N_EDGES; i += stride) {
    int r = eidx(ei, is64, i);
    int c = eidx(ei, is64, N_EDGES + i);
    atomicAdd(&wacc[r], dinv[c]);
  }
}

// ---------- exclusive scan of cnt -> rowptr (3 kernels) ----------
__global__ void scan1_kernel(const int* cnt, int* part, int* bsum, int n) {
  __shared__ int tmp[256];
  int i = blockIdx.x * 256 + threadIdx.x;
  int v = (i < n) ? cnt[i] : 0;
  tmp[threadIdx.x] = v;
  __syncthreads();
  for (int off = 1; off < 256; off <<= 1) {
    int t2 = (threadIdx.x >= off) ? tmp[threadIdx.x - off] : 0;
    __syncthreads();
    tmp[threadIdx.x] += t2;
    __syncthreads();
  }
  if (i < n) part[i] = tmp[threadIdx.x] - v;  // exclusive within block
  if (threadIdx.x == 255) bsum[blockIdx.x] = tmp[255];
}

__global__ void scan2_kernel(int* bsum, int nb) {
  __shared__ int tmp[512];
  int v = (threadIdx.x < nb) ? bsum[threadIdx.x] : 0;
  tmp[threadIdx.x] = v;
  __syncthreads();
  for (int off = 1; off < 512; off <<= 1) {
    int t2 = (threadIdx.x >= off) ? tmp[threadIdx.x - off] : 0;
    __syncthreads();
    tmp[threadIdx.x] += t2;
    __syncthreads();
  }
  if (threadIdx.x < nb) bsum[threadIdx.x] = tmp[threadIdx.x] - v;  // exclusive
}

__global__ void scan3_kernel(int* rowptr, int* cursor, const int* bsum, int n) {
  int i = blockIdx.x * 256 + threadIdx.x;
  if (i < n) {
    int v = rowptr[i] + bsum[blockIdx.x];
    rowptr[i] = v;
    cursor[i] = v;
  }
}

// ---------- CSR fill: csr[pos] = src, grouped by target ----------
__global__ void fill_kernel(const void* ei, const int* flag, int* cursor, int* csr) {
  int is64 = *flag;
  int i = blockIdx.x * blockDim.x + threadIdx.x;
  int stride = gridDim.x * blockDim.x;
  for (; i < N_EDGES; i += stride) {
    int r = eidx(ei, is64, i);
    int c = eidx(ei, is64, N_EDGES + i);
    int pos = atomicAdd(&cursor[c], 1);
    csr[pos] = r;
  }
}

// ---------- G = dinv ⊙ (x @ W1), fp32 tiled ----------
__global__ __launch_bounds__(256) void gemm_kernel(const float* __restrict__ x,
                                                   const float* __restrict__ W,
                                                   const float* __restrict__ dinv,
                                                   float* __restrict__ G) {
  __shared__ float lx[64 * IN_DIM];   // 32 KB
  __shared__ float lw[32 * HID_DIM];  // 16 KB
  const int t = threadIdx.x;
  const int row0 = blockIdx.x * 64;
  const int nrow = min(64, N_NODES - row0);

  {
    const float4* x4 = (const float4*)(x + (size_t)row0 * IN_DIM);
    float4* lx4 = (float4*)lx;
    const int tot = nrow * (IN_DIM / 4);
    for (int i = t; i < tot; i += 256) lx4[i] = x4[i];
  }

  const int c0 = (t & 31) * 4;        // 4 output cols
  const int rbase = (t >> 5) * 8;     // 8 output rows
  float4 acc[8];
#pragma unroll
  for (int i = 0; i < 8; i++) acc[i] = make_float4(0.f, 0.f, 0.f, 0.f);

  for (int kc = 0; kc < IN_DIM; kc += 32) {
    __syncthreads();
    {
      const float4* W4 = (const float4*)(W + (size_t)kc * HID_DIM);
      float4* lw4 = (float4*)lw;
      for (int i = t; i < 32 * HID_DIM / 4; i += 256) lw4[i] = W4[i];
    }
    __syncthreads();
#pragma unroll
    for (int kk = 0; kk < 32; kk += 4) {
      float4 xv[8];
#pragma unroll
      for (int i = 0; i < 8; i++)
        xv[i] = *(const float4*)&lx[(rbase + i) * IN_DIM + kc + kk];
#pragma unroll
      for (int j = 0; j < 4; j++) {
        float4 wv = *(const float4*)&lw[(kk + j) * HID_DIM + c0];
#pragma unroll
        for (int i = 0; i < 8; i++) {
          float xs = (j == 0) ? xv[i].x : (j == 1) ? xv[i].y : (j == 2) ? xv[i].z : xv[i].w;
          acc[i].x += xs * wv.x;
          acc[i].y += xs * wv.y;
          acc[i].z += xs * wv.z;
          acc[i].w += xs * wv.w;
        }
      }
    }
  }
#pragma unroll
  for (int i = 0; i < 8; i++) {
    int r = row0 + rbase + i;
    if (r < N_NODES) {
      float d = dinv[r];
      float4 v = acc[i];
      v.x *= d; v.y *= d; v.z *= d; v.w *= d;
      *(float4*)&G[(size_t)r * HID_DIM + c0] = v;
    }
  }
}

// ---------- per-node gather-sum + ReLU + weighted reduce to S[128] ----------
__global__ __launch_bounds__(256) void aggregate_kernel(
    const float* __restrict__ G, const int* __restrict__ rowptr,
    const int* __restrict__ cnt, const int* __restrict__ csr,
    const float* __restrict__ dinv, const float* __restrict__ wacc,
    const float* __restrict__ b1, float* __restrict__ S) {
  const int lane = threadIdx.x & 63;
  const int wid = blockIdx.x * (blockDim.x >> 6) + (threadIdx.x >> 6);
  const int nwaves = gridDim.x * (blockDim.x >> 6);
  const float2 b = ((const float2*)b1)[lane];
  float2 sacc = make_float2(0.f, 0.f);

  for (int c = wid; c < N_NODES; c += nwaves) {
    const int start = rowptr[c];
    const int cnum = cnt[c];
    // self loop
    float2 acc = ((const float2*)(G + (size_t)c * HID_DIM))[lane];
    for (int j0 = 0; j0 < cnum; j0 += 64) {
      int src = 0;
      if (j0 + lane < cnum) src = csr[start + j0 + lane];
      int m = min(64, cnum - j0);
      for (int i = 0; i < m; i++) {
        int s = __shfl(src, i);
        float2 g = ((const float2*)(G + (size_t)s * HID_DIM))[lane];
        acc.x += g.x;
        acc.y += g.y;
      }
    }
    float d = dinv[c];
    float hx = fmaxf(fmaf(d, acc.x, b.x), 0.f);
    float hy = fmaxf(fmaf(d, acc.y, b.y), 0.f);
    float wc = d * (wacc[c] + d);  // layer-2 weight
    sacc.x += wc * hx;
    sacc.y += wc * hy;
  }

  __shared__ float ls[HID_DIM];
  if (threadIdx.x < HID_DIM) ls[threadIdx.x] = 0.f;
  __syncthreads();
  atomicAdd(&ls[2 * lane], sacc.x);
  atomicAdd(&ls[2 * lane + 1], sacc.y);
  __syncthreads();
  if (threadIdx.x < HID_DIM) atomicAdd(&S[threadIdx.x], ls[threadIdx.x]);
}

// ---------- out[j] = (1/N) * S @ W2 + b2 ----------
__global__ void finish_kernel(const float* __restrict__ S, const float* __restrict__ W2,
                              const float* __restrict__ b2, float* __restrict__ out) {
  int j = threadIdx.x;  // 64
  float acc = 0.f;
  for (int k = 0; k < HID_DIM; k++) acc += S[k] * W2[k * OUT_DIM + j];
  out[j] = acc * (1.0f / N_NODES) + b2[j];
}

extern "C" void kernel_launch(void* const* d_in, const int* in_sizes, int n_in,
                              void* d_out, int out_size, void* d_ws, size_t ws_size,
                              hipStream_t stream) {
  const float* x  = (const float*)d_in[0];
  const void*  ei = d_in[1];
  const float* W1 = (const float*)d_in[2];
  const float* b1 = (const float*)d_in[3];
  const float* W2 = (const float*)d_in[4];
  const float* b2 = (const float*)d_in[5];
  float* out = (float*)d_out;

  char* p = (char*)d_ws;
  size_t off = 0;
  auto alloc = [&](size_t bytes) -> void* {
    void* r = p + off;
    off = (off + bytes + 15) & ~(size_t)15;
    return r;
  };
  int*   flag   = (int*)alloc(16);
  int*   cnt    = (int*)alloc((size_t)N_NODES * 4);  // zeroed region start
  float* wacc   = (float*)alloc((size_t)N_NODES * 4);
  float* S      = (float*)alloc(HID_DIM * 4);
  int*   rowptr = (int*)alloc((size_t)N_NODES * 4);
  int*   cursor = (int*)alloc((size_t)N_NODES * 4);
  float* dinv   = (float*)alloc((size_t)N_NODES * 4);
  int*   bsum   = (int*)alloc(512 * 4);
  int*   csr    = (int*)alloc((size_t)N_EDGES * 4);
  float* G      = (float*)alloc((size_t)N_NODES * HID_DIM * 4);
  (void)ws_size; (void)n_in; (void)in_sizes; (void)out_size;

  const int zwords = (N_NODES * 4 + N_NODES * 4 + HID_DIM * 4) / 4;  // cnt+wacc+S
  const int NB = (N_NODES + 255) / 256;  // 391

  zero_kernel<<<512, 256, 0, stream>>>((unsigned int*)cnt, zwords);
  detect_kernel<<<1, 256, 0, stream>>>((const unsigned int*)ei, flag);
  count_kernel<<<1024, 256, 0, stream>>>(ei, flag, cnt);
  dinv_kernel<<<NB, 256, 0, stream>>>(cnt, dinv);
  wscatter_kernel<<<1024, 256, 0, stream>>>(ei, flag, dinv, wacc);
  scan1_kernel<<<NB, 256, 0, stream>>>(cnt, rowptr, bsum, N_NODES);
  scan2_kernel<<<1, 512, 0, stream>>>(bsum, NB);
  scan3_kernel<<<NB, 256, 0, stream>>>(rowptr, cursor, bsum, N_NODES);
  fill_kernel<<<1024, 256, 0, stream>>>(ei, flag, cursor, csr);
  gemm_kernel<<<(N_NODES + 63) / 64, 256, 0, stream>>>(x, W1, dinv, G);
  aggregate_kernel<<<1024, 256, 0, stream>>>(G, rowptr, cnt, csr, dinv, wacc, b1, S);
  finish_kernel<<<1, 64, 0, stream>>>(S, W2, b2, out);
}

// Round 2
// 547.239 us; speedup vs baseline: 1.1760x; 1.1760x over previous
//
#include <hip/hip_runtime.h>

#define N_NODES 100000
#define N_EDGES 1600000
#define IN_DIM 128
#define HID_DIM 128
#define OUT_DIM 64

// ---------- helpers ----------
__device__ __forceinline__ int eidx(const void* ei, int is64, int i) {
  return is64 ? (int)((const long long*)ei)[i] : ((const int*)ei)[i];
}

// bf16 pair (packed in uint) -> float2
__device__ __forceinline__ float2 bf2f(unsigned int u) {
  float2 r;
  r.x = __uint_as_float(u << 16);
  r.y = __uint_as_float(u & 0xFFFF0000u);
  return r;
}

// float -> bf16 (round to nearest even)
__device__ __forceinline__ unsigned int f2bf(float f) {
  unsigned int u = __float_as_uint(f);
  return (u + 0x7FFFu + ((u >> 16) & 1u)) >> 16;
}

// ---------- zero workspace region ----------
__global__ void zero_kernel(unsigned int* p, int n) {
  int i = blockIdx.x * blockDim.x + threadIdx.x;
  int stride = gridDim.x * blockDim.x;
  for (; i < n; i += stride) p[i] = 0u;
}

// ---------- detect int64 vs int32 edge_index ----------
__global__ void detect_kernel(const unsigned int* ei, int* flag) {
  __shared__ int nz;
  if (threadIdx.x == 0) nz = 0;
  __syncthreads();
  unsigned int v = ei[1 + 2 * threadIdx.x];
  if (v != 0u) nz = 1;
  __syncthreads();
  if (threadIdx.x == 0) *flag = (nz == 0) ? 1 : 0;
}

// ---------- in-degree count over col ----------
__global__ void count_kernel(const void* ei, const int* flag, int* cnt) {
  int is64 = *flag;
  int i = blockIdx.x * blockDim.x + threadIdx.x;
  int stride = gridDim.x * blockDim.x;
  for (; i < N_EDGES; i += stride) {
    int c = eidx(ei, is64, N_EDGES + i);
    atomicAdd(&cnt[c], 1);
  }
}

// ---------- dinv = rsqrt(deg), deg = in-degree + self loop ----------
__global__ void dinv_kernel(const int* cnt, float* dinv) {
  int i = blockIdx.x * blockDim.x + threadIdx.x;
  if (i < N_NODES) dinv[i] = rsqrtf((float)(cnt[i] + 1));
}

// ---------- exclusive scan of cnt -> rowptr (3 kernels) ----------
__global__ void scan1_kernel(const int* cnt, int* part, int* bsum, int n) {
  __shared__ int tmp[256];
  int i = blockIdx.x * 256 + threadIdx.x;
  int v = (i < n) ? cnt[i] : 0;
  tmp[threadIdx.x] = v;
  __syncthreads();
  for (int off = 1; off < 256; off <<= 1) {
    int t2 = (threadIdx.x >= off) ? tmp[threadIdx.x - off] : 0;
    __syncthreads();
    tmp[threadIdx.x] += t2;
    __syncthreads();
  }
  if (i < n) part[i] = tmp[threadIdx.x] - v;  // exclusive within block
  if (threadIdx.x == 255) bsum[blockIdx.x] = tmp[255];
}

__global__ void scan2_kernel(int* bsum, int nb) {
  __shared__ int tmp[512];
  int v = (threadIdx.x < nb) ? bsum[threadIdx.x] : 0;
  tmp[threadIdx.x] = v;
  __syncthreads();
  for (int off = 1; off < 512; off <<= 1) {
    int t2 = (threadIdx.x >= off) ? tmp[threadIdx.x - off] : 0;
    __syncthreads();
    tmp[threadIdx.x] += t2;
    __syncthreads();
  }
  if (threadIdx.x < nb) bsum[threadIdx.x] = tmp[threadIdx.x] - v;  // exclusive
}

__global__ void scan3_kernel(int* rowptr, int* cursor, const int* bsum, int n) {
  int i = blockIdx.x * 256 + threadIdx.x;
  if (i < n) {
    int v = rowptr[i] + bsum[blockIdx.x];
    rowptr[i] = v;
    cursor[i] = v;
  }
}

// ---------- CSR fill (grouped by target) + fused wacc scatter ----------
__global__ void fill_kernel(const void* ei, const int* flag,
                            const float* __restrict__ dinv, int* cursor,
                            int* csr, float* wacc) {
  int is64 = *flag;
  int i = blockIdx.x * blockDim.x + threadIdx.x;
  int stride = gridDim.x * blockDim.x;
  for (; i < N_EDGES; i += stride) {
    int r = eidx(ei, is64, i);
    int c = eidx(ei, is64, N_EDGES + i);
    atomicAdd(&wacc[r], dinv[c]);   // layer-2 weight accumulation
    int pos = atomicAdd(&cursor[c], 1);
    csr[pos] = r;
  }
}

// ---------- G(bf16) = dinv ⊙ (x @ W1), fp32 compute ----------
__global__ __launch_bounds__(256) void gemm_kernel(const float* __restrict__ x,
                                                   const float* __restrict__ W,
                                                   const float* __restrict__ dinv,
                                                   unsigned int* __restrict__ G) {
  __shared__ float lx[64 * IN_DIM];   // 32 KB
  __shared__ float lw[32 * HID_DIM];  // 16 KB
  const int t = threadIdx.x;
  const int row0 = blockIdx.x * 64;
  const int nrow = min(64, N_NODES - row0);

  {
    const float4* x4 = (const float4*)(x + (size_t)row0 * IN_DIM);
    float4* lx4 = (float4*)lx;
    const int tot = nrow * (IN_DIM / 4);
    for (int i = t; i < tot; i += 256) lx4[i] = x4[i];
  }

  const int c0 = (t & 31) * 4;        // 4 output cols
  const int rbase = (t >> 5) * 8;     // 8 output rows
  float4 acc[8];
#pragma unroll
  for (int i = 0; i < 8; i++) acc[i] = make_float4(0.f, 0.f, 0.f, 0.f);

  for (int kc = 0; kc < IN_DIM; kc += 32) {
    __syncthreads();
    {
      const float4* W4 = (const float4*)(W + (size_t)kc * HID_DIM);
      float4* lw4 = (float4*)lw;
      for (int i = t; i < 32 * HID_DIM / 4; i += 256) lw4[i] = W4[i];
    }
    __syncthreads();
#pragma unroll
    for (int kk = 0; kk < 32; kk += 4) {
      float4 xv[8];
#pragma unroll
      for (int i = 0; i < 8; i++)
        xv[i] = *(const float4*)&lx[(rbase + i) * IN_DIM + kc + kk];
#pragma unroll
      for (int j = 0; j < 4; j++) {
        float4 wv = *(const float4*)&lw[(kk + j) * HID_DIM + c0];
#pragma unroll
        for (int i = 0; i < 8; i++) {
          float xs = (j == 0) ? xv[i].x : (j == 1) ? xv[i].y : (j == 2) ? xv[i].z : xv[i].w;
          acc[i].x += xs * wv.x;
          acc[i].y += xs * wv.y;
          acc[i].z += xs * wv.z;
          acc[i].w += xs * wv.w;
        }
      }
    }
  }
#pragma unroll
  for (int i = 0; i < 8; i++) {
    int r = row0 + rbase + i;
    if (r < N_NODES) {
      float d = dinv[r];
      float4 v = acc[i];
      uint2 pk;
      pk.x = (f2bf(v.y * d) << 16) | f2bf(v.x * d);
      pk.y = (f2bf(v.w * d) << 16) | f2bf(v.z * d);
      // row r, cols [c0, c0+4): 2 packed uints at uint-index r*64 + c0/2
      *(uint2*)&G[(size_t)r * (HID_DIM / 2) + (c0 >> 1)] = pk;
    }
  }
}

// ---------- per-node gather-sum (bf16 G) + ReLU + weighted reduce ----------
__global__ __launch_bounds__(256) void aggregate_kernel(
    const unsigned int* __restrict__ G, const int* __restrict__ rowptr,
    const int* __restrict__ cnt, const int* __restrict__ csr,
    const float* __restrict__ dinv, const float* __restrict__ wacc,
    const float* __restrict__ b1, float* __restrict__ S) {
  const int lane = threadIdx.x & 63;
  const int wid = blockIdx.x * (blockDim.x >> 6) + (threadIdx.x >> 6);
  const int nwaves = gridDim.x * (blockDim.x >> 6);
  const float2 b = ((const float2*)b1)[lane];
  float2 sacc = make_float2(0.f, 0.f);

  for (int c = wid; c < N_NODES; c += nwaves) {
    const int start = rowptr[c];
    const int cnum = cnt[c];
    // self loop
    float2 acc = bf2f(G[(size_t)c * (HID_DIM / 2) + lane]);
    for (int j0 = 0; j0 < cnum; j0 += 64) {
      int src = 0;
      if (j0 + lane < cnum) src = csr[start + j0 + lane];
      const int m = min(64, cnum - j0);
      int i = 0;
      for (; i + 4 <= m; i += 4) {
        int s0 = __shfl(src, i);
        int s1 = __shfl(src, i + 1);
        int s2 = __shfl(src, i + 2);
        int s3 = __shfl(src, i + 3);
        unsigned int g0 = G[(size_t)s0 * (HID_DIM / 2) + lane];
        unsigned int g1 = G[(size_t)s1 * (HID_DIM / 2) + lane];
        unsigned int g2 = G[(size_t)s2 * (HID_DIM / 2) + lane];
        unsigned int g3 = G[(size_t)s3 * (HID_DIM / 2) + lane];
        float2 f0 = bf2f(g0), f1 = bf2f(g1), f2 = bf2f(g2), f3 = bf2f(g3);
        acc.x += (f0.x + f1.x) + (f2.x + f3.x);
        acc.y += (f0.y + f1.y) + (f2.y + f3.y);
      }
      for (; i < m; i++) {
        int s = __shfl(src, i);
        float2 g = bf2f(G[(size_t)s * (HID_DIM / 2) + lane]);
        acc.x += g.x;
        acc.y += g.y;
      }
    }
    float d = dinv[c];
    float hx = fmaxf(fmaf(d, acc.x, b.x), 0.f);
    float hy = fmaxf(fmaf(d, acc.y, b.y), 0.f);
    float wc = d * (wacc[c] + d);  // layer-2 weight
    sacc.x += wc * hx;
    sacc.y += wc * hy;
  }

  __shared__ float ls[HID_DIM];
  if (threadIdx.x < HID_DIM) ls[threadIdx.x] = 0.f;
  __syncthreads();
  atomicAdd(&ls[2 * lane], sacc.x);
  atomicAdd(&ls[2 * lane + 1], sacc.y);
  __syncthreads();
  if (threadIdx.x < HID_DIM) atomicAdd(&S[threadIdx.x], ls[threadIdx.x]);
}

// ---------- out[j] = (1/N) * S @ W2 + b2 ----------
__global__ void finish_kernel(const float* __restrict__ S, const float* __restrict__ W2,
                              const float* __restrict__ b2, float* __restrict__ out) {
  int j = threadIdx.x;  // 64
  float acc = 0.f;
  for (int k = 0; k < HID_DIM; k++) acc += S[k] * W2[k * OUT_DIM + j];
  out[j] = acc * (1.0f / N_NODES) + b2[j];
}

extern "C" void kernel_launch(void* const* d_in, const int* in_sizes, int n_in,
                              void* d_out, int out_size, void* d_ws, size_t ws_size,
                              hipStream_t stream) {
  const float* x  = (const float*)d_in[0];
  const void*  ei = d_in[1];
  const float* W1 = (const float*)d_in[2];
  const float* b1 = (const float*)d_in[3];
  const float* W2 = (const float*)d_in[4];
  const float* b2 = (const float*)d_in[5];
  float* out = (float*)d_out;

  char* p = (char*)d_ws;
  size_t off = 0;
  auto alloc = [&](size_t bytes) -> void* {
    void* r = p + off;
    off = (off + bytes + 15) & ~(size_t)15;
    return r;
  };
  int*   flag   = (int*)alloc(16);
  int*   cnt    = (int*)alloc((size_t)N_NODES * 4);  // zeroed region start
  float* wacc   = (float*)alloc((size_t)N_NODES * 4);
  float* S      = (float*)alloc(HID_DIM * 4);
  int*   rowptr = (int*)alloc((size_t)N_NODES * 4);
  int*   cursor = (int*)alloc((size_t)N_NODES * 4);
  float* dinv   = (float*)alloc((size_t)N_NODES * 4);
  int*   bsum   = (int*)alloc(512 * 4);
  int*   csr    = (int*)alloc((size_t)N_EDGES * 4);
  unsigned int* G = (unsigned int*)alloc((size_t)N_NODES * HID_DIM * 2);  // bf16
  (void)ws_size; (void)n_in; (void)in_sizes; (void)out_size;

  const int zwords = (N_NODES * 4 + N_NODES * 4 + HID_DIM * 4) / 4;  // cnt+wacc+S
  const int NB = (N_NODES + 255) / 256;  // 391

  zero_kernel<<<512, 256, 0, stream>>>((unsigned int*)cnt, zwords);
  detect_kernel<<<1, 256, 0, stream>>>((const unsigned int*)ei, flag);
  count_kernel<<<1024, 256, 0, stream>>>(ei, flag, cnt);
  dinv_kernel<<<NB, 256, 0, stream>>>(cnt, dinv);
  scan1_kernel<<<NB, 256, 0, stream>>>(cnt, rowptr, bsum, N_NODES);
  scan2_kernel<<<1, 512, 0, stream>>>(bsum, NB);
  scan3_kernel<<<NB, 256, 0, stream>>>(rowptr, cursor, bsum, N_NODES);
  fill_kernel<<<1024, 256, 0, stream>>>(ei, flag, dinv, cursor, csr, wacc);
  gemm_kernel<<<(N_NODES + 63) / 64, 256, 0, stream>>>(x, W1, dinv, G);
  aggregate_kernel<<<2048, 256, 0, stream>>>(G, rowptr, cnt, csr, dinv, wacc, b1, S);
  finish_kernel<<<1, 64, 0, stream>>>(S, W2, b2, out);
}

// Round 3
// 535.738 us; speedup vs baseline: 1.2012x; 1.0215x over previous
//
#include <hip/hip_runtime.h>

#define N_NODES 100000
#define N_EDGES 1600000
#define IN_DIM 128
#define HID_DIM 128
#define OUT_DIM 64

// ---------- helpers ----------
// bf16 pair (packed in uint) -> float2
__device__ __forceinline__ float2 bf2f(unsigned int u) {
  float2 r;
  r.x = __uint_as_float(u << 16);
  r.y = __uint_as_float(u & 0xFFFF0000u);
  return r;
}

// float -> bf16 (round to nearest even)
__device__ __forceinline__ unsigned int f2bf(float f) {
  unsigned int u = __float_as_uint(f);
  return (u + 0x7FFFu + ((u >> 16) & 1u)) >> 16;
}

// load 4 consecutive edge indices starting at element `base` of row `half`
// (half=0 -> sources, half=1 -> targets)
__device__ __forceinline__ void load4(const void* ei, int is64, int half, int base,
                                      int* v) {
  if (is64) {
    const long long* e = (const long long*)ei + (size_t)half * N_EDGES + base;
    longlong2 a = *(const longlong2*)e;
    longlong2 b = *(const longlong2*)(e + 2);
    v[0] = (int)a.x; v[1] = (int)a.y; v[2] = (int)b.x; v[3] = (int)b.y;
  } else {
    const int* e = (const int*)ei + (size_t)half * N_EDGES + base;
    int4 a = *(const int4*)e;
    v[0] = a.x; v[1] = a.y; v[2] = a.z; v[3] = a.w;
  }
}

// ---------- zero workspace region ----------
__global__ void zero_kernel(unsigned int* p, int n) {
  int i = blockIdx.x * blockDim.x + threadIdx.x;
  int stride = gridDim.x * blockDim.x;
  for (; i < n; i += stride) p[i] = 0u;
}

// ---------- detect int64 vs int32 edge_index ----------
__global__ void detect_kernel(const unsigned int* ei, int* flag) {
  __shared__ int nz;
  if (threadIdx.x == 0) nz = 0;
  __syncthreads();
  unsigned int v = ei[1 + 2 * threadIdx.x];
  if (v != 0u) nz = 1;
  __syncthreads();
  if (threadIdx.x == 0) *flag = (nz == 0) ? 1 : 0;
}

// ---------- in-degree count over col (4 edges/thread, batched atomics) ----------
__global__ __launch_bounds__(256) void count_kernel(const void* ei, const int* flag,
                                                    int* cnt) {
  const int is64 = *flag;
  const int base = (blockIdx.x * blockDim.x + threadIdx.x) * 4;
  if (base >= N_EDGES) return;
  int c[4];
  load4(ei, is64, 1, base, c);
#pragma unroll
  for (int k = 0; k < 4; k++) atomicAdd(&cnt[c[k]], 1);
}

// ---------- dinv = rsqrt(deg), deg = in-degree + self loop ----------
__global__ void dinv_kernel(const int* cnt, float* dinv) {
  int i = blockIdx.x * blockDim.x + threadIdx.x;
  if (i < N_NODES) dinv[i] = rsqrtf((float)(cnt[i] + 1));
}

// ---------- exclusive scan of cnt -> rowptr (3 kernels) ----------
__global__ void scan1_kernel(const int* cnt, int* part, int* bsum, int n) {
  __shared__ int tmp[256];
  int i = blockIdx.x * 256 + threadIdx.x;
  int v = (i < n) ? cnt[i] : 0;
  tmp[threadIdx.x] = v;
  __syncthreads();
  for (int off = 1; off < 256; off <<= 1) {
    int t2 = (threadIdx.x >= off) ? tmp[threadIdx.x - off] : 0;
    __syncthreads();
    tmp[threadIdx.x] += t2;
    __syncthreads();
  }
  if (i < n) part[i] = tmp[threadIdx.x] - v;  // exclusive within block
  if (threadIdx.x == 255) bsum[blockIdx.x] = tmp[255];
}

__global__ void scan2_kernel(int* bsum, int nb) {
  __shared__ int tmp[512];
  int v = (threadIdx.x < nb) ? bsum[threadIdx.x] : 0;
  tmp[threadIdx.x] = v;
  __syncthreads();
  for (int off = 1; off < 512; off <<= 1) {
    int t2 = (threadIdx.x >= off) ? tmp[threadIdx.x - off] : 0;
    __syncthreads();
    tmp[threadIdx.x] += t2;
    __syncthreads();
  }
  if (threadIdx.x < nb) bsum[threadIdx.x] = tmp[threadIdx.x] - v;  // exclusive
}

__global__ void scan3_kernel(int* rowptr, int* cursor, const int* bsum, int n) {
  int i = blockIdx.x * 256 + threadIdx.x;
  if (i < n) {
    int v = rowptr[i] + bsum[blockIdx.x];
    rowptr[i] = v;
    cursor[i] = v;
  }
}

// ---------- CSR fill + fused wacc scatter (4 edges/thread, batched) ----------
__global__ __launch_bounds__(256) void fill_kernel(const void* ei, const int* flag,
                                                   const float* __restrict__ dinv,
                                                   int* cursor, int* csr, float* wacc) {
  const int is64 = *flag;
  const int base = (blockIdx.x * blockDim.x + threadIdx.x) * 4;
  if (base >= N_EDGES) return;
  int r[4], c[4];
  load4(ei, is64, 0, base, r);
  load4(ei, is64, 1, base, c);
  float dv[4];
#pragma unroll
  for (int k = 0; k < 4; k++) dv[k] = dinv[c[k]];
#pragma unroll
  for (int k = 0; k < 4; k++) atomicAdd(&wacc[r[k]], dv[k]);  // no return needed
  int pos[4];
#pragma unroll
  for (int k = 0; k < 4; k++) pos[k] = atomicAdd(&cursor[c[k]], 1);
#pragma unroll
  for (int k = 0; k < 4; k++) csr[pos[k]] = r[k];
}

// ---------- G(bf16) = dinv ⊙ (x @ W1), fp32 compute ----------
__global__ __launch_bounds__(256) void gemm_kernel(const float* __restrict__ x,
                                                   const float* __restrict__ W,
                                                   const float* __restrict__ dinv,
                                                   unsigned int* __restrict__ G) {
  __shared__ float lx[64 * IN_DIM];   // 32 KB
  __shared__ float lw[32 * HID_DIM];  // 16 KB
  const int t = threadIdx.x;
  const int row0 = blockIdx.x * 64;
  const int nrow = min(64, N_NODES - row0);

  {
    const float4* x4 = (const float4*)(x + (size_t)row0 * IN_DIM);
    float4* lx4 = (float4*)lx;
    const int tot = nrow * (IN_DIM / 4);
    for (int i = t; i < tot; i += 256) lx4[i] = x4[i];
  }

  const int c0 = (t & 31) * 4;        // 4 output cols
  const int rbase = (t >> 5) * 8;     // 8 output rows
  float4 acc[8];
#pragma unroll
  for (int i = 0; i < 8; i++) acc[i] = make_float4(0.f, 0.f, 0.f, 0.f);

  for (int kc = 0; kc < IN_DIM; kc += 32) {
    __syncthreads();
    {
      const float4* W4 = (const float4*)(W + (size_t)kc * HID_DIM);
      float4* lw4 = (float4*)lw;
      for (int i = t; i < 32 * HID_DIM / 4; i += 256) lw4[i] = W4[i];
    }
    __syncthreads();
#pragma unroll
    for (int kk = 0; kk < 32; kk += 4) {
      float4 xv[8];
#pragma unroll
      for (int i = 0; i < 8; i++)
        xv[i] = *(const float4*)&lx[(rbase + i) * IN_DIM + kc + kk];
#pragma unroll
      for (int j = 0; j < 4; j++) {
        float4 wv = *(const float4*)&lw[(kk + j) * HID_DIM + c0];
#pragma unroll
        for (int i = 0; i < 8; i++) {
          float xs = (j == 0) ? xv[i].x : (j == 1) ? xv[i].y : (j == 2) ? xv[i].z : xv[i].w;
          acc[i].x += xs * wv.x;
          acc[i].y += xs * wv.y;
          acc[i].z += xs * wv.z;
          acc[i].w += xs * wv.w;
        }
      }
    }
  }
#pragma unroll
  for (int i = 0; i < 8; i++) {
    int r = row0 + rbase + i;
    if (r < N_NODES) {
      float d = dinv[r];
      float4 v = acc[i];
      uint2 pk;
      pk.x = (f2bf(v.y * d) << 16) | f2bf(v.x * d);
      pk.y = (f2bf(v.w * d) << 16) | f2bf(v.z * d);
      *(uint2*)&G[(size_t)r * (HID_DIM / 2) + (c0 >> 1)] = pk;
    }
  }
}

// ---------- per-node gather-sum (bf16 G) + ReLU + weighted reduce ----------
__global__ __launch_bounds__(256) void aggregate_kernel(
    const unsigned int* __restrict__ G, const int* __restrict__ rowptr,
    const int* __restrict__ cnt, const int* __restrict__ csr,
    const float* __restrict__ dinv, const float* __restrict__ wacc,
    const float* __restrict__ b1, float* __restrict__ S) {
  const int lane = threadIdx.x & 63;
  const int wid = blockIdx.x * (blockDim.x >> 6) + (threadIdx.x >> 6);
  const int nwaves = gridDim.x * (blockDim.x >> 6);
  const float2 b = ((const float2*)b1)[lane];
  float2 sacc = make_float2(0.f, 0.f);

  for (int c = wid; c < N_NODES; c += nwaves) {
    const int start = rowptr[c];
    const int cnum = cnt[c];
    // self loop
    float2 acc = bf2f(G[(size_t)c * (HID_DIM / 2) + lane]);
    for (int j0 = 0; j0 < cnum; j0 += 64) {
      int src = 0;
      if (j0 + lane < cnum) src = csr[start + j0 + lane];
      const int m = min(64, cnum - j0);
      int i = 0;
      for (; i + 4 <= m; i += 4) {
        int s0 = __shfl(src, i);
        int s1 = __shfl(src, i + 1);
        int s2 = __shfl(src, i + 2);
        int s3 = __shfl(src, i + 3);
        unsigned int g0 = G[(size_t)s0 * (HID_DIM / 2) + lane];
        unsigned int g1 = G[(size_t)s1 * (HID_DIM / 2) + lane];
        unsigned int g2 = G[(size_t)s2 * (HID_DIM / 2) + lane];
        unsigned int g3 = G[(size_t)s3 * (HID_DIM / 2) + lane];
        float2 f0 = bf2f(g0), f1 = bf2f(g1), f2 = bf2f(g2), f3 = bf2f(g3);
        acc.x += (f0.x + f1.x) + (f2.x + f3.x);
        acc.y += (f0.y + f1.y) + (f2.y + f3.y);
      }
      for (; i < m; i++) {
        int s = __shfl(src, i);
        float2 g = bf2f(G[(size_t)s * (HID_DIM / 2) + lane]);
        acc.x += g.x;
        acc.y += g.y;
      }
    }
    float d = dinv[c];
    float hx = fmaxf(fmaf(d, acc.x, b.x), 0.f);
    float hy = fmaxf(fmaf(d, acc.y, b.y), 0.f);
    float wc = d * (wacc[c] + d);  // layer-2 weight
    sacc.x += wc * hx;
    sacc.y += wc * hy;
  }

  __shared__ float ls[HID_DIM];
  if (threadIdx.x < HID_DIM) ls[threadIdx.x] = 0.f;
  __syncthreads();
  atomicAdd(&ls[2 * lane], sacc.x);
  atomicAdd(&ls[2 * lane + 1], sacc.y);
  __syncthreads();
  if (threadIdx.x < HID_DIM) atomicAdd(&S[threadIdx.x], ls[threadIdx.x]);
}

// ---------- out[j] = (1/N) * S @ W2 + b2 ----------
__global__ void finish_kernel(const float* __restrict__ S, const float* __restrict__ W2,
                              const float* __restrict__ b2, float* __restrict__ out) {
  int j = threadIdx.x;  // 64
  float acc = 0.f;
  for (int k = 0; k < HID_DIM; k++) acc += S[k] * W2[k * OUT_DIM + j];
  out[j] = acc * (1.0f / N_NODES) + b2[j];
}

extern "C" void kernel_launch(void* const* d_in, const int* in_sizes, int n_in,
                              void* d_out, int out_size, void* d_ws, size_t ws_size,
                              hipStream_t stream) {
  const float* x  = (const float*)d_in[0];
  const void*  ei = d_in[1];
  const float* W1 = (const float*)d_in[2];
  const float* b1 = (const float*)d_in[3];
  const float* W2 = (const float*)d_in[4];
  const float* b2 = (const float*)d_in[5];
  float* out = (float*)d_out;

  char* p = (char*)d_ws;
  size_t off = 0;
  auto alloc = [&](size_t bytes) -> void* {
    void* r = p + off;
    off = (off + bytes + 15) & ~(size_t)15;
    return r;
  };
  int*   flag   = (int*)alloc(16);
  int*   cnt    = (int*)alloc((size_t)N_NODES * 4);  // zeroed region start
  float* wacc   = (float*)alloc((size_t)N_NODES * 4);
  float* S      = (float*)alloc(HID_DIM * 4);
  int*   rowptr = (int*)alloc((size_t)N_NODES * 4);
  int*   cursor = (int*)alloc((size_t)N_NODES * 4);
  float* dinv   = (float*)alloc((size_t)N_NODES * 4);
  int*   bsum   = (int*)alloc(512 * 4);
  int*   csr    = (int*)alloc((size_t)N_EDGES * 4);
  unsigned int* G = (unsigned int*)alloc((size_t)N_NODES * HID_DIM * 2);  // bf16
  (void)ws_size; (void)n_in; (void)in_sizes; (void)out_size;

  const int zwords = (N_NODES * 4 + N_NODES * 4 + HID_DIM * 4) / 4;  // cnt+wacc+S
  const int NB = (N_NODES + 255) / 256;   // 391
  const int EB4 = (N_EDGES / 4 + 255) / 256;  // 1563 blocks: 4 edges/thread

  zero_kernel<<<512, 256, 0, stream>>>((unsigned int*)cnt, zwords);
  detect_kernel<<<1, 256, 0, stream>>>((const unsigned int*)ei, flag);
  count_kernel<<<EB4, 256, 0, stream>>>(ei, flag, cnt);
  dinv_kernel<<<NB, 256, 0, stream>>>(cnt, dinv);
  scan1_kernel<<<NB, 256, 0, stream>>>(cnt, rowptr, bsum, N_NODES);
  scan2_kernel<<<1, 512, 0, stream>>>(bsum, NB);
  scan3_kernel<<<NB, 256, 0, stream>>>(rowptr, cursor, bsum, N_NODES);
  fill_kernel<<<EB4, 256, 0, stream>>>(ei, flag, dinv, cursor, csr, wacc);
  gemm_kernel<<<(N_NODES + 63) / 64, 256, 0, stream>>>(x, W1, dinv, G);
  aggregate_kernel<<<2048, 256, 0, stream>>>(G, rowptr, cnt, csr, dinv, wacc, b1, S);
  finish_kernel<<<1, 64, 0, stream>>>(S, W2, b2, out);
}

// Round 4
// 504.095 us; speedup vs baseline: 1.2766x; 1.0628x over previous
//
#include <hip/hip_runtime.h>

#define N_NODES 100000
#define N_EDGES 1600000
#define IN_DIM 128
#define HID_DIM 128
#define OUT_DIM 64
#define PAD 16  // one counter per 64B line

// ---------- helpers ----------
__device__ __forceinline__ float2 bf2f(unsigned int u) {
  float2 r;
  r.x = __uint_as_float(u << 16);
  r.y = __uint_as_float(u & 0xFFFF0000u);
  return r;
}

__device__ __forceinline__ unsigned int f2bf(float f) {
  unsigned int u = __float_as_uint(f);
  return (u + 0x7FFFu + ((u >> 16) & 1u)) >> 16;
}

__device__ __forceinline__ void load4(const void* ei, int is64, int half, int base,
                                      int* v) {
  if (is64) {
    const long long* e = (const long long*)ei + (size_t)half * N_EDGES + base;
    longlong2 a = *(const longlong2*)e;
    longlong2 b = *(const longlong2*)(e + 2);
    v[0] = (int)a.x; v[1] = (int)a.y; v[2] = (int)b.x; v[3] = (int)b.y;
  } else {
    const int* e = (const int*)ei + (size_t)half * N_EDGES + base;
    int4 a = *(const int4*)e;
    v[0] = a.x; v[1] = a.y; v[2] = a.z; v[3] = a.w;
  }
}

// ---------- zero workspace region ----------
__global__ void zero_kernel(uint4* p, int n4) {
  int i = blockIdx.x * blockDim.x + threadIdx.x;
  int stride = gridDim.x * blockDim.x;
  uint4 z = make_uint4(0u, 0u, 0u, 0u);
  for (; i < n4; i += stride) p[i] = z;
}

// ---------- detect int64 vs int32 edge_index ----------
__global__ void detect_kernel(const unsigned int* ei, int* flag) {
  __shared__ int nz;
  if (threadIdx.x == 0) nz = 0;
  __syncthreads();
  unsigned int v = ei[1 + 2 * threadIdx.x];
  if (v != 0u) nz = 1;
  __syncthreads();
  if (threadIdx.x == 0) *flag = (nz == 0) ? 1 : 0;
}

// ---------- in-degree count over col (padded counters) ----------
__global__ __launch_bounds__(256) void count_kernel(const void* ei, const int* flag,
                                                    int* cnt_pad) {
  const int is64 = *flag;
  const int base = (blockIdx.x * blockDim.x + threadIdx.x) * 4;
  if (base >= N_EDGES) return;
  int c[4];
  load4(ei, is64, 1, base, c);
#pragma unroll
  for (int k = 0; k < 4; k++) atomicAdd(&cnt_pad[c[k] << 4], 1);
}

// ---------- dinv = rsqrt(deg); also compact padded counts for the scan ----------
__global__ void dinv_kernel(const int* cnt_pad, float* dinv, int* cnt_dense) {
  int i = blockIdx.x * blockDim.x + threadIdx.x;
  if (i < N_NODES) {
    int c = cnt_pad[i << 4];
    dinv[i] = rsqrtf((float)(c + 1));
    cnt_dense[i] = c;
  }
}

// ---------- exclusive scan of cnt_dense -> rowptr (3 kernels) ----------
__global__ void scan1_kernel(const int* cnt, int* part, int* bsum, int n) {
  __shared__ int tmp[256];
  int i = blockIdx.x * 256 + threadIdx.x;
  int v = (i < n) ? cnt[i] : 0;
  tmp[threadIdx.x] = v;
  __syncthreads();
  for (int off = 1; off < 256; off <<= 1) {
    int t2 = (threadIdx.x >= off) ? tmp[threadIdx.x - off] : 0;
    __syncthreads();
    tmp[threadIdx.x] += t2;
    __syncthreads();
  }
  if (i < n) part[i] = tmp[threadIdx.x] - v;  // exclusive within block
  if (threadIdx.x == 255) bsum[blockIdx.x] = tmp[255];
}

__global__ void scan2_kernel(int* bsum, int nb) {
  __shared__ int tmp[512];
  int v = (threadIdx.x < nb) ? bsum[threadIdx.x] : 0;
  tmp[threadIdx.x] = v;
  __syncthreads();
  for (int off = 1; off < 512; off <<= 1) {
    int t2 = (threadIdx.x >= off) ? tmp[threadIdx.x - off] : 0;
    __syncthreads();
    tmp[threadIdx.x] += t2;
    __syncthreads();
  }
  if (threadIdx.x < nb) bsum[threadIdx.x] = tmp[threadIdx.x] - v;  // exclusive
}

__global__ void scan3_kernel(int* rowptr, int* cursor_pad, const int* bsum, int n) {
  int i = blockIdx.x * 256 + threadIdx.x;
  if (i < n) {
    int v = rowptr[i] + bsum[blockIdx.x];
    rowptr[i] = v;
    cursor_pad[i << 4] = v;
  }
  if (blockIdx.x == 0 && threadIdx.x == 0) rowptr[N_NODES] = N_EDGES;  // sentinel
}

// ---------- CSR fill + fused wacc scatter (padded counters) ----------
__global__ __launch_bounds__(256) void fill_kernel(const void* ei, const int* flag,
                                                   const float* __restrict__ dinv,
                                                   int* cursor_pad, int* csr,
                                                   float* wacc_pad) {
  const int is64 = *flag;
  const int base = (blockIdx.x * blockDim.x + threadIdx.x) * 4;
  if (base >= N_EDGES) return;
  int r[4], c[4];
  load4(ei, is64, 0, base, r);
  load4(ei, is64, 1, base, c);
  float dv[4];
#pragma unroll
  for (int k = 0; k < 4; k++) dv[k] = dinv[c[k]];
#pragma unroll
  for (int k = 0; k < 4; k++) atomicAdd(&wacc_pad[r[k] << 4], dv[k]);
  int pos[4];
#pragma unroll
  for (int k = 0; k < 4; k++) pos[k] = atomicAdd(&cursor_pad[c[k] << 4], 1);
#pragma unroll
  for (int k = 0; k < 4; k++) csr[pos[k]] = r[k];
}

// ---------- G(bf16) = dinv ⊙ (x @ W1), fp32 compute ----------
__global__ __launch_bounds__(256) void gemm_kernel(const float* __restrict__ x,
                                                   const float* __restrict__ W,
                                                   const float* __restrict__ dinv,
                                                   unsigned int* __restrict__ G) {
  __shared__ float lx[64 * IN_DIM];   // 32 KB
  __shared__ float lw[32 * HID_DIM];  // 16 KB
  const int t = threadIdx.x;
  const int row0 = blockIdx.x * 64;
  const int nrow = min(64, N_NODES - row0);

  {
    const float4* x4 = (const float4*)(x + (size_t)row0 * IN_DIM);
    float4* lx4 = (float4*)lx;
    const int tot = nrow * (IN_DIM / 4);
    for (int i = t; i < tot; i += 256) lx4[i] = x4[i];
  }

  const int c0 = (t & 31) * 4;        // 4 output cols
  const int rbase = (t >> 5) * 8;     // 8 output rows
  float4 acc[8];
#pragma unroll
  for (int i = 0; i < 8; i++) acc[i] = make_float4(0.f, 0.f, 0.f, 0.f);

  for (int kc = 0; kc < IN_DIM; kc += 32) {
    __syncthreads();
    {
      const float4* W4 = (const float4*)(W + (size_t)kc * HID_DIM);
      float4* lw4 = (float4*)lw;
      for (int i = t; i < 32 * HID_DIM / 4; i += 256) lw4[i] = W4[i];
    }
    __syncthreads();
#pragma unroll
    for (int kk = 0; kk < 32; kk += 4) {
      float4 xv[8];
#pragma unroll
      for (int i = 0; i < 8; i++)
        xv[i] = *(const float4*)&lx[(rbase + i) * IN_DIM + kc + kk];
#pragma unroll
      for (int j = 0; j < 4; j++) {
        float4 wv = *(const float4*)&lw[(kk + j) * HID_DIM + c0];
#pragma unroll
        for (int i = 0; i < 8; i++) {
          float xs = (j == 0) ? xv[i].x : (j == 1) ? xv[i].y : (j == 2) ? xv[i].z : xv[i].w;
          acc[i].x += xs * wv.x;
          acc[i].y += xs * wv.y;
          acc[i].z += xs * wv.z;
          acc[i].w += xs * wv.w;
        }
      }
    }
  }
#pragma unroll
  for (int i = 0; i < 8; i++) {
    int r = row0 + rbase + i;
    if (r < N_NODES) {
      float d = dinv[r];
      float4 v = acc[i];
      uint2 pk;
      pk.x = (f2bf(v.y * d) << 16) | f2bf(v.x * d);
      pk.y = (f2bf(v.w * d) << 16) | f2bf(v.z * d);
      *(uint2*)&G[(size_t)r * (HID_DIM / 2) + (c0 >> 1)] = pk;
    }
  }
}

// ---------- per-node gather-sum (bf16 G) + ReLU + weighted reduce ----------
__global__ __launch_bounds__(256) void aggregate_kernel(
    const unsigned int* __restrict__ G, const int* __restrict__ rowptr,
    const int* __restrict__ csr, const float* __restrict__ dinv,
    const float* __restrict__ wacc_pad, const float* __restrict__ b1,
    float* __restrict__ S) {
  const int lane = threadIdx.x & 63;
  const int wid = blockIdx.x * (blockDim.x >> 6) + (threadIdx.x >> 6);
  const int nwaves = gridDim.x * (blockDim.x >> 6);
  const float2 b = ((const float2*)b1)[lane];
  float2 sacc = make_float2(0.f, 0.f);

  for (int c = wid; c < N_NODES; c += nwaves) {
    const int start = rowptr[c];
    const int cnum = rowptr[c + 1] - start;
    // self loop
    float2 acc = bf2f(G[(size_t)c * (HID_DIM / 2) + lane]);
    for (int j0 = 0; j0 < cnum; j0 += 64) {
      int src = 0;
      if (j0 + lane < cnum) src = csr[start + j0 + lane];
      const int m = min(64, cnum - j0);
      int i = 0;
      for (; i + 4 <= m; i += 4) {
        int s0 = __shfl(src, i);
        int s1 = __shfl(src, i + 1);
        int s2 = __shfl(src, i + 2);
        int s3 = __shfl(src, i + 3);
        unsigned int g0 = G[(size_t)s0 * (HID_DIM / 2) + lane];
        unsigned int g1 = G[(size_t)s1 * (HID_DIM / 2) + lane];
        unsigned int g2 = G[(size_t)s2 * (HID_DIM / 2) + lane];
        unsigned int g3 = G[(size_t)s3 * (HID_DIM / 2) + lane];
        float2 f0 = bf2f(g0), f1 = bf2f(g1), f2 = bf2f(g2), f3 = bf2f(g3);
        acc.x += (f0.x + f1.x) + (f2.x + f3.x);
        acc.y += (f0.y + f1.y) + (f2.y + f3.y);
      }
      for (; i < m; i++) {
        int s = __shfl(src, i);
        float2 g = bf2f(G[(size_t)s * (HID_DIM / 2) + lane]);
        acc.x += g.x;
        acc.y += g.y;
      }
    }
    float d = dinv[c];
    float hx = fmaxf(fmaf(d, acc.x, b.x), 0.f);
    float hy = fmaxf(fmaf(d, acc.y, b.y), 0.f);
    float wc = d * (wacc_pad[c << 4] + d);  // layer-2 weight
    sacc.x += wc * hx;
    sacc.y += wc * hy;
  }

  __shared__ float ls[HID_DIM];
  if (threadIdx.x < HID_DIM) ls[threadIdx.x] = 0.f;
  __syncthreads();
  atomicAdd(&ls[2 * lane], sacc.x);
  atomicAdd(&ls[2 * lane + 1], sacc.y);
  __syncthreads();
  if (threadIdx.x < HID_DIM) atomicAdd(&S[threadIdx.x], ls[threadIdx.x]);
}

// ---------- out[j] = (1/N) * S @ W2 + b2 ----------
__global__ void finish_kernel(const float* __restrict__ S, const float* __restrict__ W2,
                              const float* __restrict__ b2, float* __restrict__ out) {
  int j = threadIdx.x;  // 64
  float acc = 0.f;
  for (int k = 0; k < HID_DIM; k++) acc += S[k] * W2[k * OUT_DIM + j];
  out[j] = acc * (1.0f / N_NODES) + b2[j];
}

extern "C" void kernel_launch(void* const* d_in, const int* in_sizes, int n_in,
                              void* d_out, int out_size, void* d_ws, size_t ws_size,
                              hipStream_t stream) {
  const float* x  = (const float*)d_in[0];
  const void*  ei = d_in[1];
  const float* W1 = (const float*)d_in[2];
  const float* b1 = (const float*)d_in[3];
  const float* W2 = (const float*)d_in[4];
  const float* b2 = (const float*)d_in[5];
  float* out = (float*)d_out;

  char* p = (char*)d_ws;
  size_t off = 0;
  auto alloc = [&](size_t bytes) -> void* {
    void* r = p + off;
    off = (off + bytes + 63) & ~(size_t)63;
    return r;
  };
  // zeroed region: cnt_pad + wacc_pad + S (contiguous)
  int*   cnt_pad    = (int*)alloc((size_t)N_NODES * PAD * 4);    // 6.4 MB
  float* wacc_pad   = (float*)alloc((size_t)N_NODES * PAD * 4);  // 6.4 MB
  float* S          = (float*)alloc(HID_DIM * 4);
  int*   flag       = (int*)alloc(64);
  int*   rowptr     = (int*)alloc(((size_t)N_NODES + 1) * 4);
  int*   cursor_pad = (int*)alloc((size_t)N_NODES * PAD * 4);    // 6.4 MB
  float* dinv       = (float*)alloc((size_t)N_NODES * 4);
  int*   cnt_dense  = (int*)alloc((size_t)N_NODES * 4);
  int*   bsum       = (int*)alloc(512 * 4);
  int*   csr        = (int*)alloc((size_t)N_EDGES * 4);          // 6.4 MB
  unsigned int* G   = (unsigned int*)alloc((size_t)N_NODES * HID_DIM * 2);  // 25.6 MB
  (void)ws_size; (void)n_in; (void)in_sizes; (void)out_size;

  const int zw4 = (N_NODES * PAD * 4 * 2 + HID_DIM * 4) / 16;  // uint4 count
  const int NB = (N_NODES + 255) / 256;       // 391
  const int EB4 = (N_EDGES / 4 + 255) / 256;  // 1563 blocks: 4 edges/thread

  zero_kernel<<<2048, 256, 0, stream>>>((uint4*)cnt_pad, zw4);
  detect_kernel<<<1, 256, 0, stream>>>((const unsigned int*)ei, flag);
  count_kernel<<<EB4, 256, 0, stream>>>(ei, flag, cnt_pad);
  dinv_kernel<<<NB, 256, 0, stream>>>(cnt_pad, dinv, cnt_dense);
  scan1_kernel<<<NB, 256, 0, stream>>>(cnt_dense, rowptr, bsum, N_NODES);
  scan2_kernel<<<1, 512, 0, stream>>>(bsum, NB);
  scan3_kernel<<<NB, 256, 0, stream>>>(rowptr, cursor_pad, bsum, N_NODES);
  fill_kernel<<<EB4, 256, 0, stream>>>(ei, flag, dinv, cursor_pad, csr, wacc_pad);
  gemm_kernel<<<(N_NODES + 63) / 64, 256, 0, stream>>>(x, W1, dinv, G);
  aggregate_kernel<<<2048, 256, 0, stream>>>(G, rowptr, csr, dinv, wacc_pad, b1, S);
  finish_kernel<<<1, 64, 0, stream>>>(S, W2, b2, out);
}

// Round 5
// 344.525 us; speedup vs baseline: 1.8679x; 1.4632x over previous
//
#include <hip/hip_runtime.h>

#define N_NODES 100000
#define N_EDGES 1600000
#define IN_DIM 128
#define HID_DIM 128
#define OUT_DIM 64
#define BKT_SHIFT 7
#define BKT_SIZE 128
#define NBKT ((N_NODES + BKT_SIZE - 1) / BKT_SIZE)  // 782
#define B1 128                                       // blocks in hist/scatter passes
#define HIST_N (NBKT * B1)                           // 100096

// ---------- helpers ----------
__device__ __forceinline__ float2 bf2f(unsigned int u) {
  float2 r;
  r.x = __uint_as_float(u << 16);
  r.y = __uint_as_float(u & 0xFFFF0000u);
  return r;
}

__device__ __forceinline__ unsigned int f2bf(float f) {
  unsigned int u = __float_as_uint(f);
  return (u + 0x7FFFu + ((u >> 16) & 1u)) >> 16;
}

__device__ __forceinline__ void load4(const void* ei, int is64, int half, int base,
                                      int* v) {
  if (is64) {
    const long long* e = (const long long*)ei + (size_t)half * N_EDGES + base;
    longlong2 a = *(const longlong2*)e;
    longlong2 b = *(const longlong2*)(e + 2);
    v[0] = (int)a.x; v[1] = (int)a.y; v[2] = (int)b.x; v[3] = (int)b.y;
  } else {
    const int* e = (const int*)ei + (size_t)half * N_EDGES + base;
    int4 a = *(const int4*)e;
    v[0] = a.x; v[1] = a.y; v[2] = a.z; v[3] = a.w;
  }
}

// ---------- zero S ----------
__global__ void zeroS_kernel(float* S) {
  if (threadIdx.x < HID_DIM) S[threadIdx.x] = 0.f;
}

// ---------- detect int64 vs int32 edge_index ----------
__global__ void detect_kernel(const unsigned int* ei, int* flag) {
  __shared__ int nz;
  if (threadIdx.x == 0) nz = 0;
  __syncthreads();
  unsigned int v = ei[1 + 2 * threadIdx.x];
  if (v != 0u) nz = 1;
  __syncthreads();
  if (threadIdx.x == 0) *flag = (nz == 0) ? 1 : 0;
}

// ---------- pass A: per-block bucket histograms (dst and src) ----------
__global__ __launch_bounds__(256) void hist_kernel(const void* ei, const int* flag,
                                                   int* histD, int* histS) {
  __shared__ int hd[NBKT], hs[NBKT];
  for (int k = threadIdx.x; k < NBKT; k += 256) { hd[k] = 0; hs[k] = 0; }
  __syncthreads();
  const int is64 = *flag;
  for (int g = blockIdx.x * 256 + threadIdx.x; g < N_EDGES / 4; g += B1 * 256) {
    int r[4], c[4];
    load4(ei, is64, 0, g * 4, r);
    load4(ei, is64, 1, g * 4, c);
#pragma unroll
    for (int k = 0; k < 4; k++) {
      atomicAdd(&hd[c[k] >> BKT_SHIFT], 1);
      atomicAdd(&hs[r[k] >> BKT_SHIFT], 1);
    }
  }
  __syncthreads();
  for (int k = threadIdx.x; k < NBKT; k += 256) {
    histD[k * B1 + blockIdx.x] = hd[k];
    histS[k * B1 + blockIdx.x] = hs[k];
  }
}

// ---------- exclusive scan (in-place capable) ----------
__global__ void scan1_kernel(const int* cnt, int* part, int* bsum, int n) {
  __shared__ int tmp[256];
  int i = blockIdx.x * 256 + threadIdx.x;
  int v = (i < n) ? cnt[i] : 0;
  tmp[threadIdx.x] = v;
  __syncthreads();
  for (int off = 1; off < 256; off <<= 1) {
    int t2 = (threadIdx.x >= off) ? tmp[threadIdx.x - off] : 0;
    __syncthreads();
    tmp[threadIdx.x] += t2;
    __syncthreads();
  }
  if (i < n) part[i] = tmp[threadIdx.x] - v;  // exclusive within block
  if (threadIdx.x == 255) bsum[blockIdx.x] = tmp[255];
}

__global__ void scan2_kernel(int* bsum, int nb) {
  __shared__ int tmp[512];
  int v = (threadIdx.x < nb) ? bsum[threadIdx.x] : 0;
  tmp[threadIdx.x] = v;
  __syncthreads();
  for (int off = 1; off < 512; off <<= 1) {
    int t2 = (threadIdx.x >= off) ? tmp[threadIdx.x - off] : 0;
    __syncthreads();
    tmp[threadIdx.x] += t2;
    __syncthreads();
  }
  if (threadIdx.x < nb) bsum[threadIdx.x] = tmp[threadIdx.x] - v;  // exclusive
}

__global__ void scan3_kernel(int* arr, const int* bsum, int n) {
  int i = blockIdx.x * 256 + threadIdx.x;
  if (i < n) arr[i] += bsum[blockIdx.x];
}

// ---------- pass B: scatter packed pairs into bucket partitions ----------
__global__ __launch_bounds__(256) void scatter_kernel(const void* ei, const int* flag,
                                                      const int* histD, const int* histS,
                                                      unsigned int* pairsD,
                                                      unsigned int* pairsS) {
  __shared__ int cd[NBKT], cs[NBKT];
  for (int k = threadIdx.x; k < NBKT; k += 256) {
    cd[k] = histD[k * B1 + blockIdx.x];
    cs[k] = histS[k * B1 + blockIdx.x];
  }
  __syncthreads();
  const int is64 = *flag;
  for (int g = blockIdx.x * 256 + threadIdx.x; g < N_EDGES / 4; g += B1 * 256) {
    int r[4], c[4];
    load4(ei, is64, 0, g * 4, r);
    load4(ei, is64, 1, g * 4, c);
#pragma unroll
    for (int k = 0; k < 4; k++) {
      int pd = atomicAdd(&cd[c[k] >> BKT_SHIFT], 1);
      pairsD[pd] = ((unsigned int)(c[k] & (BKT_SIZE - 1)) << 17) | (unsigned int)r[k];
      int ps = atomicAdd(&cs[r[k] >> BKT_SHIFT], 1);
      pairsS[ps] = ((unsigned int)(r[k] & (BKT_SIZE - 1)) << 17) | (unsigned int)c[k];
    }
  }
}

// ---------- pass C: per-bucket exact CSR + rowptr + dinv ----------
__global__ __launch_bounds__(256) void csr_kernel(const int* histD,
                                                  const unsigned int* pairsD,
                                                  int* rowptr, int* csr, float* dinv) {
  __shared__ int cnt[BKT_SIZE], sc[BKT_SIZE], cur[BKT_SIZE];
  const int k = blockIdx.x;
  const int base = histD[k * B1];
  const int end = (k == NBKT - 1) ? N_EDGES : histD[(k + 1) * B1];
  const int nseg = end - base;
  const int l = threadIdx.x;
  if (l < BKT_SIZE) cnt[l] = 0;
  __syncthreads();
  for (int i = l; i < nseg; i += 256) atomicAdd(&cnt[pairsD[base + i] >> 17], 1);
  __syncthreads();
  if (l < BKT_SIZE) sc[l] = cnt[l];
  __syncthreads();
  for (int off = 1; off < BKT_SIZE; off <<= 1) {
    int v = (l < BKT_SIZE && l >= off) ? sc[l - off] : 0;
    __syncthreads();
    if (l < BKT_SIZE) sc[l] += v;
    __syncthreads();
  }
  if (l < BKT_SIZE) {
    int excl = sc[l] - cnt[l];
    cur[l] = base + excl;
    int v = k * BKT_SIZE + l;
    if (v < N_NODES) {
      rowptr[v] = base + excl;
      dinv[v] = rsqrtf((float)(cnt[l] + 1));
    }
  }
  if (k == NBKT - 1 && l == 0) rowptr[N_NODES] = N_EDGES;
  __syncthreads();
  for (int i = l; i < nseg; i += 256) {
    unsigned int pk = pairsD[base + i];
    int pos = atomicAdd(&cur[pk >> 17], 1);
    csr[pos] = (int)(pk & 0x1FFFFu);
  }
}

// ---------- pass C2: per-src-bucket wacc = sum of dinv[dst] over out-edges ----------
__global__ __launch_bounds__(256) void outsum_kernel(const int* histS,
                                                     const unsigned int* pairsS,
                                                     const float* __restrict__ dinv,
                                                     float* wacc) {
  __shared__ float fb[BKT_SIZE];
  const int k = blockIdx.x;
  const int base = histS[k * B1];
  const int end = (k == NBKT - 1) ? N_EDGES : histS[(k + 1) * B1];
  if (threadIdx.x < BKT_SIZE) fb[threadIdx.x] = 0.f;
  __syncthreads();
  for (int i = base + threadIdx.x; i < end; i += 256) {
    unsigned int pk = pairsS[i];
    atomicAdd(&fb[pk >> 17], dinv[pk & 0x1FFFFu]);
  }
  __syncthreads();
  int v = k * BKT_SIZE + threadIdx.x;
  if (threadIdx.x < BKT_SIZE && v < N_NODES) wacc[v] = fb[threadIdx.x];
}

// ---------- G(bf16) = dinv ⊙ (x @ W1), fp32 compute ----------
__global__ __launch_bounds__(256) void gemm_kernel(const float* __restrict__ x,
                                                   const float* __restrict__ W,
                                                   const float* __restrict__ dinv,
                                                   unsigned int* __restrict__ G) {
  __shared__ float lx[64 * IN_DIM];   // 32 KB
  __shared__ float lw[32 * HID_DIM];  // 16 KB
  const int t = threadIdx.x;
  const int row0 = blockIdx.x * 64;
  const int nrow = min(64, N_NODES - row0);

  {
    const float4* x4 = (const float4*)(x + (size_t)row0 * IN_DIM);
    float4* lx4 = (float4*)lx;
    const int tot = nrow * (IN_DIM / 4);
    for (int i = t; i < tot; i += 256) lx4[i] = x4[i];
  }

  const int c0 = (t & 31) * 4;        // 4 output cols
  const int rbase = (t >> 5) * 8;     // 8 output rows
  float4 acc[8];
#pragma unroll
  for (int i = 0; i < 8; i++) acc[i] = make_float4(0.f, 0.f, 0.f, 0.f);

  for (int kc = 0; kc < IN_DIM; kc += 32) {
    __syncthreads();
    {
      const float4* W4 = (const float4*)(W + (size_t)kc * HID_DIM);
      float4* lw4 = (float4*)lw;
      for (int i = t; i < 32 * HID_DIM / 4; i += 256) lw4[i] = W4[i];
    }
    __syncthreads();
#pragma unroll
    for (int kk = 0; kk < 32; kk += 4) {
      float4 xv[8];
#pragma unroll
      for (int i = 0; i < 8; i++)
        xv[i] = *(const float4*)&lx[(rbase + i) * IN_DIM + kc + kk];
#pragma unroll
      for (int j = 0; j < 4; j++) {
        float4 wv = *(const float4*)&lw[(kk + j) * HID_DIM + c0];
#pragma unroll
        for (int i = 0; i < 8; i++) {
          float xs = (j == 0) ? xv[i].x : (j == 1) ? xv[i].y : (j == 2) ? xv[i].z : xv[i].w;
          acc[i].x += xs * wv.x;
          acc[i].y += xs * wv.y;
          acc[i].z += xs * wv.z;
          acc[i].w += xs * wv.w;
        }
      }
    }
  }
#pragma unroll
  for (int i = 0; i < 8; i++) {
    int r = row0 + rbase + i;
    if (r < N_NODES) {
      float d = dinv[r];
      float4 v = acc[i];
      uint2 pk;
      pk.x = (f2bf(v.y * d) << 16) | f2bf(v.x * d);
      pk.y = (f2bf(v.w * d) << 16) | f2bf(v.z * d);
      *(uint2*)&G[(size_t)r * (HID_DIM / 2) + (c0 >> 1)] = pk;
    }
  }
}

// ---------- per-node gather-sum (bf16 G) + ReLU + weighted reduce ----------
__global__ __launch_bounds__(256) void aggregate_kernel(
    const unsigned int* __restrict__ G, const int* __restrict__ rowptr,
    const int* __restrict__ csr, const float* __restrict__ dinv,
    const float* __restrict__ wacc, const float* __restrict__ b1,
    float* __restrict__ S) {
  const int lane = threadIdx.x & 63;
  const int wid = blockIdx.x * (blockDim.x >> 6) + (threadIdx.x >> 6);
  const int nwaves = gridDim.x * (blockDim.x >> 6);
  const float2 b = ((const float2*)b1)[lane];
  float2 sacc = make_float2(0.f, 0.f);

  for (int c = wid; c < N_NODES; c += nwaves) {
    const int start = rowptr[c];
    const int cnum = rowptr[c + 1] - start;
    // self loop
    float2 acc = bf2f(G[(size_t)c * (HID_DIM / 2) + lane]);
    for (int j0 = 0; j0 < cnum; j0 += 64) {
      int src = 0;
      if (j0 + lane < cnum) src = csr[start + j0 + lane];
      const int m = min(64, cnum - j0);
      int i = 0;
      for (; i + 4 <= m; i += 4) {
        int s0 = __shfl(src, i);
        int s1 = __shfl(src, i + 1);
        int s2 = __shfl(src, i + 2);
        int s3 = __shfl(src, i + 3);
        unsigned int g0 = G[(size_t)s0 * (HID_DIM / 2) + lane];
        unsigned int g1 = G[(size_t)s1 * (HID_DIM / 2) + lane];
        unsigned int g2 = G[(size_t)s2 * (HID_DIM / 2) + lane];
        unsigned int g3 = G[(size_t)s3 * (HID_DIM / 2) + lane];
        float2 f0 = bf2f(g0), f1 = bf2f(g1), f2 = bf2f(g2), f3 = bf2f(g3);
        acc.x += (f0.x + f1.x) + (f2.x + f3.x);
        acc.y += (f0.y + f1.y) + (f2.y + f3.y);
      }
      for (; i < m; i++) {
        int s = __shfl(src, i);
        float2 g = bf2f(G[(size_t)s * (HID_DIM / 2) + lane]);
        acc.x += g.x;
        acc.y += g.y;
      }
    }
    float d = dinv[c];
    float hx = fmaxf(fmaf(d, acc.x, b.x), 0.f);
    float hy = fmaxf(fmaf(d, acc.y, b.y), 0.f);
    float wc = d * (wacc[c] + d);  // layer-2 weight
    sacc.x += wc * hx;
    sacc.y += wc * hy;
  }

  __shared__ float ls[HID_DIM];
  if (threadIdx.x < HID_DIM) ls[threadIdx.x] = 0.f;
  __syncthreads();
  atomicAdd(&ls[2 * lane], sacc.x);
  atomicAdd(&ls[2 * lane + 1], sacc.y);
  __syncthreads();
  if (threadIdx.x < HID_DIM) atomicAdd(&S[threadIdx.x], ls[threadIdx.x]);
}

// ---------- out[j] = (1/N) * S @ W2 + b2 ----------
__global__ void finish_kernel(const float* __restrict__ S, const float* __restrict__ W2,
                              const float* __restrict__ b2, float* __restrict__ out) {
  int j = threadIdx.x;  // 64
  float acc = 0.f;
  for (int k = 0; k < HID_DIM; k++) acc += S[k] * W2[k * OUT_DIM + j];
  out[j] = acc * (1.0f / N_NODES) + b2[j];
}

extern "C" void kernel_launch(void* const* d_in, const int* in_sizes, int n_in,
                              void* d_out, int out_size, void* d_ws, size_t ws_size,
                              hipStream_t stream) {
  const float* x  = (const float*)d_in[0];
  const void*  ei = d_in[1];
  const float* W1 = (const float*)d_in[2];
  const float* b1 = (const float*)d_in[3];
  const float* W2 = (const float*)d_in[4];
  const float* b2 = (const float*)d_in[5];
  float* out = (float*)d_out;

  char* p = (char*)d_ws;
  size_t off = 0;
  auto alloc = [&](size_t bytes) -> void* {
    void* r = p + off;
    off = (off + bytes + 63) & ~(size_t)63;
    return r;
  };
  int*   flag   = (int*)alloc(64);
  int*   histD  = (int*)alloc((size_t)HIST_N * 4);            // 400 KB
  int*   histS  = (int*)alloc((size_t)HIST_N * 4);            // 400 KB
  int*   bsum   = (int*)alloc(512 * 4);
  unsigned int* pairsD = (unsigned int*)alloc((size_t)N_EDGES * 4);  // 6.4 MB
  unsigned int* pairsS = (unsigned int*)alloc((size_t)N_EDGES * 4);  // 6.4 MB
  int*   rowptr = (int*)alloc(((size_t)N_NODES + 1) * 4);
  int*   csr    = (int*)alloc((size_t)N_EDGES * 4);           // 6.4 MB
  float* dinv   = (float*)alloc((size_t)N_NODES * 4);
  float* wacc   = (float*)alloc((size_t)N_NODES * 4);
  float* S      = (float*)alloc(HID_DIM * 4);
  unsigned int* G = (unsigned int*)alloc((size_t)N_NODES * HID_DIM * 2);  // 25.6 MB
  (void)ws_size; (void)n_in; (void)in_sizes; (void)out_size;

  const int NBH = HIST_N / 256;  // 391, exact

  zeroS_kernel<<<1, 128, 0, stream>>>(S);
  detect_kernel<<<1, 256, 0, stream>>>((const unsigned int*)ei, flag);
  hist_kernel<<<B1, 256, 0, stream>>>(ei, flag, histD, histS);
  // scan histD in place
  scan1_kernel<<<NBH, 256, 0, stream>>>(histD, histD, bsum, HIST_N);
  scan2_kernel<<<1, 512, 0, stream>>>(bsum, NBH);
  scan3_kernel<<<NBH, 256, 0, stream>>>(histD, bsum, HIST_N);
  // scan histS in place
  scan1_kernel<<<NBH, 256, 0, stream>>>(histS, histS, bsum, HIST_N);
  scan2_kernel<<<1, 512, 0, stream>>>(bsum, NBH);
  scan3_kernel<<<NBH, 256, 0, stream>>>(histS, bsum, HIST_N);
  scatter_kernel<<<B1, 256, 0, stream>>>(ei, flag, histD, histS, pairsD, pairsS);
  csr_kernel<<<NBKT, 256, 0, stream>>>(histD, pairsD, rowptr, csr, dinv);
  outsum_kernel<<<NBKT, 256, 0, stream>>>(histS, pairsS, dinv, wacc);
  gemm_kernel<<<(N_NODES + 63) / 64, 256, 0, stream>>>(x, W1, dinv, G);
  aggregate_kernel<<<2048, 256, 0, stream>>>(G, rowptr, csr, dinv, wacc, b1, S);
  finish_kernel<<<1, 64, 0, stream>>>(S, W2, b2, out);
}

// Round 6
// 313.046 us; speedup vs baseline: 2.0557x; 1.1006x over previous
//
#include <hip/hip_runtime.h>

#define N_NODES 100000
#define N_EDGES 1600000
#define IN_DIM 128
#define HID_DIM 128
#define OUT_DIM 64
#define BKT_SHIFT 7
#define BKT_SIZE 128
#define NBKT ((N_NODES + BKT_SIZE - 1) / BKT_SIZE)  // 782
#define B1 128                                       // blocks in hist/scatter passes
#define HIST_N (NBKT * B1)                           // 100096
#define HIST_N2 (2 * HIST_N)                         // 200192 (D then S)

typedef float v2f __attribute__((ext_vector_type(2)));

// ---------- helpers ----------
__device__ __forceinline__ void load4(const void* ei, int is64, int half, int base,
                                      int* v) {
  if (is64) {
    const long long* e = (const long long*)ei + (size_t)half * N_EDGES + base;
    longlong2 a = *(const longlong2*)e;
    longlong2 b = *(const longlong2*)(e + 2);
    v[0] = (int)a.x; v[1] = (int)a.y; v[2] = (int)b.x; v[3] = (int)b.y;
  } else {
    const int* e = (const int*)ei + (size_t)half * N_EDGES + base;
    int4 a = *(const int4*)e;
    v[0] = a.x; v[1] = a.y; v[2] = a.z; v[3] = a.w;
  }
}

// ---------- detect int64 vs int32 edge_index + zero S ----------
__global__ void detect_kernel(const unsigned int* ei, int* flag, float* S) {
  __shared__ int nz;
  if (threadIdx.x == 0) nz = 0;
  __syncthreads();
  unsigned int v = ei[1 + 2 * threadIdx.x];
  if (v != 0u) nz = 1;
  if (threadIdx.x < HID_DIM) S[threadIdx.x] = 0.f;
  __syncthreads();
  if (threadIdx.x == 0) *flag = (nz == 0) ? 1 : 0;
}

// ---------- pass A: per-block bucket histograms (dst then src, concatenated) ----
__global__ __launch_bounds__(256) void hist_kernel(const void* ei, const int* flag,
                                                   int* hist) {
  __shared__ int hd[NBKT], hs[NBKT];
  for (int k = threadIdx.x; k < NBKT; k += 256) { hd[k] = 0; hs[k] = 0; }
  __syncthreads();
  const int is64 = *flag;
  for (int g = blockIdx.x * 256 + threadIdx.x; g < N_EDGES / 4; g += B1 * 256) {
    int r[4], c[4];
    load4(ei, is64, 0, g * 4, r);
    load4(ei, is64, 1, g * 4, c);
#pragma unroll
    for (int k = 0; k < 4; k++) {
      atomicAdd(&hd[c[k] >> BKT_SHIFT], 1);
      atomicAdd(&hs[r[k] >> BKT_SHIFT], 1);
    }
  }
  __syncthreads();
  for (int k = threadIdx.x; k < NBKT; k += 256) {
    hist[k * B1 + blockIdx.x] = hd[k];
    hist[HIST_N + k * B1 + blockIdx.x] = hs[k];
  }
}

// ---------- exclusive scan over HIST_N2 (3 kernels, in place) ----------
__global__ void scan1_kernel(const int* cnt, int* part, int* bsum, int n) {
  __shared__ int tmp[256];
  int i = blockIdx.x * 256 + threadIdx.x;
  int v = (i < n) ? cnt[i] : 0;
  tmp[threadIdx.x] = v;
  __syncthreads();
  for (int off = 1; off < 256; off <<= 1) {
    int t2 = (threadIdx.x >= off) ? tmp[threadIdx.x - off] : 0;
    __syncthreads();
    tmp[threadIdx.x] += t2;
    __syncthreads();
  }
  if (i < n) part[i] = tmp[threadIdx.x] - v;  // exclusive within block
  if (threadIdx.x == 255) bsum[blockIdx.x] = tmp[255];
}

__global__ void scan2_kernel(int* bsum, int nb) {
  __shared__ int tmp[1024];
  int v = (threadIdx.x < nb) ? bsum[threadIdx.x] : 0;
  tmp[threadIdx.x] = v;
  __syncthreads();
  for (int off = 1; off < 1024; off <<= 1) {
    int t2 = (threadIdx.x >= off) ? tmp[threadIdx.x - off] : 0;
    __syncthreads();
    tmp[threadIdx.x] += t2;
    __syncthreads();
  }
  if (threadIdx.x < nb) bsum[threadIdx.x] = tmp[threadIdx.x] - v;  // exclusive
}

__global__ void scan3_kernel(int* arr, const int* bsum, int n) {
  int i = blockIdx.x * 256 + threadIdx.x;
  if (i < n) arr[i] += bsum[blockIdx.x];
}

// ---------- pass B: scatter packed pairs; D-partition [0,E), S-partition [E,2E) --
__global__ __launch_bounds__(256) void scatter_kernel(const void* ei, const int* flag,
                                                      const int* hist,
                                                      unsigned int* pairs) {
  __shared__ int cd[NBKT], cs[NBKT];
  for (int k = threadIdx.x; k < NBKT; k += 256) {
    cd[k] = hist[k * B1 + blockIdx.x];
    cs[k] = hist[HIST_N + k * B1 + blockIdx.x];
  }
  __syncthreads();
  const int is64 = *flag;
  for (int g = blockIdx.x * 256 + threadIdx.x; g < N_EDGES / 4; g += B1 * 256) {
    int r[4], c[4];
    load4(ei, is64, 0, g * 4, r);
    load4(ei, is64, 1, g * 4, c);
#pragma unroll
    for (int k = 0; k < 4; k++) {
      int pd = atomicAdd(&cd[c[k] >> BKT_SHIFT], 1);
      pairs[pd] = ((unsigned int)(c[k] & (BKT_SIZE - 1)) << 17) | (unsigned int)r[k];
      int ps = atomicAdd(&cs[r[k] >> BKT_SHIFT], 1);
      pairs[ps] = ((unsigned int)(r[k] & (BKT_SIZE - 1)) << 17) | (unsigned int)c[k];
    }
  }
}

// ---------- pass C: per-bucket exact CSR + rowptr + dinv ----------
__global__ __launch_bounds__(256) void csr_kernel(const int* hist,
                                                  const unsigned int* pairs,
                                                  int* rowptr, int* csr, float* dinv) {
  __shared__ int cnt[BKT_SIZE], sc[BKT_SIZE], cur[BKT_SIZE];
  const int k = blockIdx.x;
  const int base = hist[k * B1];
  const int end = (k == NBKT - 1) ? N_EDGES : hist[(k + 1) * B1];
  const int nseg = end - base;
  const int l = threadIdx.x;
  if (l < BKT_SIZE) cnt[l] = 0;
  __syncthreads();
  for (int i = l; i < nseg; i += 256) atomicAdd(&cnt[pairs[base + i] >> 17], 1);
  __syncthreads();
  if (l < BKT_SIZE) sc[l] = cnt[l];
  __syncthreads();
  for (int off = 1; off < BKT_SIZE; off <<= 1) {
    int v = (l < BKT_SIZE && l >= off) ? sc[l - off] : 0;
    __syncthreads();
    if (l < BKT_SIZE) sc[l] += v;
    __syncthreads();
  }
  if (l < BKT_SIZE) {
    int excl = sc[l] - cnt[l];
    cur[l] = base + excl;
    int v = k * BKT_SIZE + l;
    if (v < N_NODES) {
      rowptr[v] = base + excl;
      dinv[v] = rsqrtf((float)(cnt[l] + 1));
    }
  }
  if (k == NBKT - 1 && l == 0) rowptr[N_NODES] = N_EDGES;
  __syncthreads();
  for (int i = l; i < nseg; i += 256) {
    unsigned int pk = pairs[base + i];
    int pos = atomicAdd(&cur[pk >> 17], 1);
    csr[pos] = (int)(pk & 0x1FFFFu);
  }
}

// ---------- pass C2: per-src-bucket wacc = sum of dinv[dst] over out-edges ------
__global__ __launch_bounds__(256) void outsum_kernel(const int* hist,
                                                     const unsigned int* pairs,
                                                     const float* __restrict__ dinv,
                                                     float* wacc) {
  __shared__ float fb[BKT_SIZE];
  const int k = blockIdx.x;
  const int base = hist[HIST_N + k * B1];
  const int end = (k == NBKT - 1) ? 2 * N_EDGES : hist[HIST_N + (k + 1) * B1];
  if (threadIdx.x < BKT_SIZE) fb[threadIdx.x] = 0.f;
  __syncthreads();
  for (int i = base + threadIdx.x; i < end; i += 256) {
    unsigned int pk = pairs[i];
    atomicAdd(&fb[pk >> 17], dinv[pk & 0x1FFFFu]);
  }
  __syncthreads();
  int v = k * BKT_SIZE + threadIdx.x;
  if (threadIdx.x < BKT_SIZE && v < N_NODES) wacc[v] = fb[threadIdx.x];
}

// ---------- G(fp8 e4m3) = dinv ⊙ (x @ W1), fp32 compute, HW fp8 encode ----------
__global__ __launch_bounds__(256) void gemm_kernel(const float* __restrict__ x,
                                                   const float* __restrict__ W,
                                                   const float* __restrict__ dinv,
                                                   unsigned int* __restrict__ G) {
  __shared__ float lx[64 * IN_DIM];   // 32 KB
  __shared__ float lw[32 * HID_DIM];  // 16 KB
  const int t = threadIdx.x;
  const int row0 = blockIdx.x * 64;
  const int nrow = min(64, N_NODES - row0);

  {
    const float4* x4 = (const float4*)(x + (size_t)row0 * IN_DIM);
    float4* lx4 = (float4*)lx;
    const int tot = nrow * (IN_DIM / 4);
    for (int i = t; i < tot; i += 256) lx4[i] = x4[i];
  }

  const int c0 = (t & 31) * 4;        // 4 output cols
  const int rbase = (t >> 5) * 8;     // 8 output rows
  float4 acc[8];
#pragma unroll
  for (int i = 0; i < 8; i++) acc[i] = make_float4(0.f, 0.f, 0.f, 0.f);

  for (int kc = 0; kc < IN_DIM; kc += 32) {
    __syncthreads();
    {
      const float4* W4 = (const float4*)(W + (size_t)kc * HID_DIM);
      float4* lw4 = (float4*)lw;
      for (int i = t; i < 32 * HID_DIM / 4; i += 256) lw4[i] = W4[i];
    }
    __syncthreads();
#pragma unroll
    for (int kk = 0; kk < 32; kk += 4) {
      float4 xv[8];
#pragma unroll
      for (int i = 0; i < 8; i++)
        xv[i] = *(const float4*)&lx[(rbase + i) * IN_DIM + kc + kk];
#pragma unroll
      for (int j = 0; j < 4; j++) {
        float4 wv = *(const float4*)&lw[(kk + j) * HID_DIM + c0];
#pragma unroll
        for (int i = 0; i < 8; i++) {
          float xs = (j == 0) ? xv[i].x : (j == 1) ? xv[i].y : (j == 2) ? xv[i].z : xv[i].w;
          acc[i].x += xs * wv.x;
          acc[i].y += xs * wv.y;
          acc[i].z += xs * wv.z;
          acc[i].w += xs * wv.w;
        }
      }
    }
  }
#pragma unroll
  for (int i = 0; i < 8; i++) {
    int r = row0 + rbase + i;
    if (r < N_NODES) {
      float d = dinv[r];
      float4 v = acc[i];
      int pk = __builtin_amdgcn_cvt_pk_fp8_f32(v.x * d, v.y * d, 0, false);
      pk = __builtin_amdgcn_cvt_pk_fp8_f32(v.z * d, v.w * d, pk, true);
      // row r = 32 uints (128 fp8); this thread owns cols [c0, c0+4)
      G[(size_t)r * (HID_DIM / 4) + (c0 >> 2)] = (unsigned int)pk;
    }
  }
}

// ---------- per-node gather-sum (fp8 G) + ReLU + weighted reduce ----------
__global__ __launch_bounds__(256) void aggregate_kernel(
    const unsigned short* __restrict__ G, const int* __restrict__ rowptr,
    const int* __restrict__ csr, const float* __restrict__ dinv,
    const float* __restrict__ wacc, const float* __restrict__ b1,
    float* __restrict__ S) {
  const int lane = threadIdx.x & 63;
  const int wid = blockIdx.x * (blockDim.x >> 6) + (threadIdx.x >> 6);
  const int nwaves = gridDim.x * (blockDim.x >> 6);
  const float2 b = ((const float2*)b1)[lane];
  float2 sacc = make_float2(0.f, 0.f);

  for (int c = wid; c < N_NODES; c += nwaves) {
    const int start = rowptr[c];
    const int cnum = rowptr[c + 1] - start;
    // self loop: lane handles cols 2*lane, 2*lane+1 (row = 64 ushorts)
    v2f acc = __builtin_amdgcn_cvt_pk_f32_fp8((int)G[(size_t)c * 64 + lane], false);
    for (int j0 = 0; j0 < cnum; j0 += 64) {
      int src = 0;
      if (j0 + lane < cnum) src = csr[start + j0 + lane];
      const int m = min(64, cnum - j0);
      int i = 0;
      for (; i + 4 <= m; i += 4) {
        int s0 = __shfl(src, i);
        int s1 = __shfl(src, i + 1);
        int s2 = __shfl(src, i + 2);
        int s3 = __shfl(src, i + 3);
        int g0 = G[(size_t)s0 * 64 + lane];
        int g1 = G[(size_t)s1 * 64 + lane];
        int g2 = G[(size_t)s2 * 64 + lane];
        int g3 = G[(size_t)s3 * 64 + lane];
        v2f f0 = __builtin_amdgcn_cvt_pk_f32_fp8(g0, false);
        v2f f1 = __builtin_amdgcn_cvt_pk_f32_fp8(g1, false);
        v2f f2 = __builtin_amdgcn_cvt_pk_f32_fp8(g2, false);
        v2f f3 = __builtin_amdgcn_cvt_pk_f32_fp8(g3, false);
        acc += (f0 + f1) + (f2 + f3);
      }
      for (; i < m; i++) {
        int s = __shfl(src, i);
        acc += __builtin_amdgcn_cvt_pk_f32_fp8((int)G[(size_t)s * 64 + lane], false);
      }
    }
    float d = dinv[c];
    float hx = fmaxf(fmaf(d, acc.x, b.x), 0.f);
    float hy = fmaxf(fmaf(d, acc.y, b.y), 0.f);
    float wc = d * (wacc[c] + d);  // layer-2 weight
    sacc.x += wc * hx;
    sacc.y += wc * hy;
  }

  __shared__ float ls[HID_DIM];
  if (threadIdx.x < HID_DIM) ls[threadIdx.x] = 0.f;
  __syncthreads();
  atomicAdd(&ls[2 * lane], sacc.x);
  atomicAdd(&ls[2 * lane + 1], sacc.y);
  __syncthreads();
  if (threadIdx.x < HID_DIM) atomicAdd(&S[threadIdx.x], ls[threadIdx.x]);
}

// ---------- out[j] = (1/N) * S @ W2 + b2 ----------
__global__ void finish_kernel(const float* __restrict__ S, const float* __restrict__ W2,
                              const float* __restrict__ b2, float* __restrict__ out) {
  int j = threadIdx.x;  // 64
  float acc = 0.f;
  for (int k = 0; k < HID_DIM; k++) acc += S[k] * W2[k * OUT_DIM + j];
  out[j] = acc * (1.0f / N_NODES) + b2[j];
}

extern "C" void kernel_launch(void* const* d_in, const int* in_sizes, int n_in,
                              void* d_out, int out_size, void* d_ws, size_t ws_size,
                              hipStream_t stream) {
  const float* x  = (const float*)d_in[0];
  const void*  ei = d_in[1];
  const float* W1 = (const float*)d_in[2];
  const float* b1 = (const float*)d_in[3];
  const float* W2 = (const float*)d_in[4];
  const float* b2 = (const float*)d_in[5];
  float* out = (float*)d_out;

  char* p = (char*)d_ws;
  size_t off = 0;
  auto alloc = [&](size_t bytes) -> void* {
    void* r = p + off;
    off = (off + bytes + 63) & ~(size_t)63;
    return r;
  };
  int*   flag   = (int*)alloc(64);
  int*   hist   = (int*)alloc((size_t)HIST_N2 * 4);                // 800 KB
  int*   bsum   = (int*)alloc(1024 * 4);
  unsigned int* pairs = (unsigned int*)alloc((size_t)2 * N_EDGES * 4);  // 12.8 MB
  int*   rowptr = (int*)alloc(((size_t)N_NODES + 1) * 4);
  int*   csr    = (int*)alloc((size_t)N_EDGES * 4);                // 6.4 MB
  float* dinv   = (float*)alloc((size_t)N_NODES * 4);
  float* wacc   = (float*)alloc((size_t)N_NODES * 4);
  float* S      = (float*)alloc(HID_DIM * 4);
  unsigned int* G = (unsigned int*)alloc((size_t)N_NODES * HID_DIM);  // 12.8 MB fp8
  (void)ws_size; (void)n_in; (void)in_sizes; (void)out_size;

  const int NBH = HIST_N2 / 256;  // 782, exact

  detect_kernel<<<1, 256, 0, stream>>>((const unsigned int*)ei, flag, S);
  hist_kernel<<<B1, 256, 0, stream>>>(ei, flag, hist);
  scan1_kernel<<<NBH, 256, 0, stream>>>(hist, hist, bsum, HIST_N2);
  scan2_kernel<<<1, 1024, 0, stream>>>(bsum, NBH);
  scan3_kernel<<<NBH, 256, 0, stream>>>(hist, bsum, HIST_N2);
  scatter_kernel<<<B1, 256, 0, stream>>>(ei, flag, hist, pairs);
  csr_kernel<<<NBKT, 256, 0, stream>>>(hist, pairs, rowptr, csr, dinv);
  outsum_kernel<<<NBKT, 256, 0, stream>>>(hist, pairs, dinv, wacc);
  gemm_kernel<<<(N_NODES + 63) / 64, 256, 0, stream>>>(x, W1, dinv, G);
  aggregate_kernel<<<2048, 256, 0, stream>>>((const unsigned short*)G, rowptr, csr,
                                             dinv, wacc, b1, S);
  finish_kernel<<<1, 64, 0, stream>>>(S, W2, b2, out);
}

// Round 7
// 299.090 us; speedup vs baseline: 2.1517x; 1.0467x over previous
//
#include <hip/hip_runtime.h>

#define N_NODES 100000
#define N_EDGES 1600000
#define IN_DIM 128
#define HID_DIM 128
#define OUT_DIM 64
#define BKT_SHIFT 8
#define BKT_SIZE 256
#define NBKT ((N_NODES + BKT_SIZE - 1) / BKT_SIZE)  // 391
#define B1 256                                       // blocks in hist/scatter passes
#define HIST_N (NBKT * B1)                           // 100096
#define HIST_N2 (2 * HIST_N)                         // 200192 (D then S)

typedef float v2f __attribute__((ext_vector_type(2)));

// ---------- helpers ----------
__device__ __forceinline__ void load4(const void* ei, int is64, int half, int base,
                                      int* v) {
  if (is64) {
    const long long* e = (const long long*)ei + (size_t)half * N_EDGES + base;
    longlong2 a = *(const longlong2*)e;
    longlong2 b = *(const longlong2*)(e + 2);
    v[0] = (int)a.x; v[1] = (int)a.y; v[2] = (int)b.x; v[3] = (int)b.y;
  } else {
    const int* e = (const int*)ei + (size_t)half * N_EDGES + base;
    int4 a = *(const int4*)e;
    v[0] = a.x; v[1] = a.y; v[2] = a.z; v[3] = a.w;
  }
}

// ---------- detect int64 vs int32 edge_index + zero S ----------
__global__ void detect_kernel(const unsigned int* ei, int* flag, float* S) {
  __shared__ int nz;
  if (threadIdx.x == 0) nz = 0;
  __syncthreads();
  unsigned int v = ei[1 + 2 * threadIdx.x];
  if (v != 0u) nz = 1;
  if (threadIdx.x < HID_DIM) S[threadIdx.x] = 0.f;
  __syncthreads();
  if (threadIdx.x == 0) *flag = (nz == 0) ? 1 : 0;
}

// ---------- pass A: per-block bucket histograms (dst then src, concatenated) ----
__global__ __launch_bounds__(256) void hist_kernel(const void* ei, const int* flag,
                                                   int* hist) {
  __shared__ int hd[NBKT], hs[NBKT];
  for (int k = threadIdx.x; k < NBKT; k += 256) { hd[k] = 0; hs[k] = 0; }
  __syncthreads();
  const int is64 = *flag;
  for (int g = blockIdx.x * 256 + threadIdx.x; g < N_EDGES / 4; g += B1 * 256) {
    int r[4], c[4];
    load4(ei, is64, 0, g * 4, r);
    load4(ei, is64, 1, g * 4, c);
#pragma unroll
    for (int k = 0; k < 4; k++) {
      atomicAdd(&hd[c[k] >> BKT_SHIFT], 1);
      atomicAdd(&hs[r[k] >> BKT_SHIFT], 1);
    }
  }
  __syncthreads();
  for (int k = threadIdx.x; k < NBKT; k += 256) {
    hist[k * B1 + blockIdx.x] = hd[k];
    hist[HIST_N + k * B1 + blockIdx.x] = hs[k];
  }
}

// ---------- exclusive scan over HIST_N2 (3 kernels, in place) ----------
__global__ void scan1_kernel(const int* cnt, int* part, int* bsum, int n) {
  __shared__ int tmp[256];
  int i = blockIdx.x * 256 + threadIdx.x;
  int v = (i < n) ? cnt[i] : 0;
  tmp[threadIdx.x] = v;
  __syncthreads();
  for (int off = 1; off < 256; off <<= 1) {
    int t2 = (threadIdx.x >= off) ? tmp[threadIdx.x - off] : 0;
    __syncthreads();
    tmp[threadIdx.x] += t2;
    __syncthreads();
  }
  if (i < n) part[i] = tmp[threadIdx.x] - v;  // exclusive within block
  if (threadIdx.x == 255) bsum[blockIdx.x] = tmp[255];
}

__global__ void scan2_kernel(int* bsum, int nb) {
  __shared__ int tmp[1024];
  int v = (threadIdx.x < nb) ? bsum[threadIdx.x] : 0;
  tmp[threadIdx.x] = v;
  __syncthreads();
  for (int off = 1; off < 1024; off <<= 1) {
    int t2 = (threadIdx.x >= off) ? tmp[threadIdx.x - off] : 0;
    __syncthreads();
    tmp[threadIdx.x] += t2;
    __syncthreads();
  }
  if (threadIdx.x < nb) bsum[threadIdx.x] = tmp[threadIdx.x] - v;  // exclusive
}

__global__ void scan3_kernel(int* arr, const int* bsum, int n) {
  int i = blockIdx.x * 256 + threadIdx.x;
  if (i < n) arr[i] += bsum[blockIdx.x];
}

// ---------- pass B: scatter packed pairs; D-partition [0,E), S-partition [E,2E) --
__global__ __launch_bounds__(256) void scatter_kernel(const void* ei, const int* flag,
                                                      const int* hist,
                                                      unsigned int* pairs) {
  __shared__ int cd[NBKT], cs[NBKT];
  for (int k = threadIdx.x; k < NBKT; k += 256) {
    cd[k] = hist[k * B1 + blockIdx.x];
    cs[k] = hist[HIST_N + k * B1 + blockIdx.x];
  }
  __syncthreads();
  const int is64 = *flag;
  for (int g = blockIdx.x * 256 + threadIdx.x; g < N_EDGES / 4; g += B1 * 256) {
    int r[4], c[4];
    load4(ei, is64, 0, g * 4, r);
    load4(ei, is64, 1, g * 4, c);
#pragma unroll
    for (int k = 0; k < 4; k++) {
      int pd = atomicAdd(&cd[c[k] >> BKT_SHIFT], 1);
      pairs[pd] = ((unsigned int)(c[k] & (BKT_SIZE - 1)) << 17) | (unsigned int)r[k];
      int ps = atomicAdd(&cs[r[k] >> BKT_SHIFT], 1);
      pairs[ps] = ((unsigned int)(r[k] & (BKT_SIZE - 1)) << 17) | (unsigned int)c[k];
    }
  }
}

// ---------- pass C: per-bucket exact CSR + rowptr + dinv ----------
__global__ __launch_bounds__(256) void csr_kernel(const int* hist,
                                                  const unsigned int* pairs,
                                                  int* rowptr, int* csr, float* dinv) {
  __shared__ int cnt[BKT_SIZE], sc[BKT_SIZE], cur[BKT_SIZE];
  const int k = blockIdx.x;
  const int base = hist[k * B1];
  const int end = (k == NBKT - 1) ? N_EDGES : hist[(k + 1) * B1];
  const int nseg = end - base;
  const int l = threadIdx.x;
  cnt[l] = 0;
  __syncthreads();
  for (int i = l; i < nseg; i += 256) atomicAdd(&cnt[pairs[base + i] >> 17], 1);
  __syncthreads();
  sc[l] = cnt[l];
  __syncthreads();
  for (int off = 1; off < BKT_SIZE; off <<= 1) {
    int v = (l >= off) ? sc[l - off] : 0;
    __syncthreads();
    sc[l] += v;
    __syncthreads();
  }
  {
    int excl = sc[l] - cnt[l];
    cur[l] = base + excl;
    int v = k * BKT_SIZE + l;
    if (v < N_NODES) {
      rowptr[v] = base + excl;
      dinv[v] = rsqrtf((float)(cnt[l] + 1));
    }
  }
  if (k == NBKT - 1 && l == 0) rowptr[N_NODES] = N_EDGES;
  __syncthreads();
  for (int i = l; i < nseg; i += 256) {
    unsigned int pk = pairs[base + i];
    int pos = atomicAdd(&cur[pk >> 17], 1);
    csr[pos] = (int)(pk & 0x1FFFFu);
  }
}

// ---------- pass C2: per-src-bucket wacc = sum of dinv[dst] over out-edges ------
__global__ __launch_bounds__(256) void outsum_kernel(const int* hist,
                                                     const unsigned int* pairs,
                                                     const float* __restrict__ dinv,
                                                     float* wacc) {
  __shared__ float fb[BKT_SIZE];
  const int k = blockIdx.x;
  const int base = hist[HIST_N + k * B1];
  const int end = (k == NBKT - 1) ? 2 * N_EDGES : hist[HIST_N + (k + 1) * B1];
  fb[threadIdx.x] = 0.f;
  __syncthreads();
  for (int i = base + threadIdx.x; i < end; i += 256) {
    unsigned int pk = pairs[i];
    atomicAdd(&fb[pk >> 17], dinv[pk & 0x1FFFFu]);
  }
  __syncthreads();
  int v = k * BKT_SIZE + threadIdx.x;
  if (v < N_NODES) wacc[v] = fb[threadIdx.x];
}

// ---------- G(fp8 e4m3) = dinv ⊙ (x @ W1), fp32 compute, HW fp8 encode ----------
__global__ __launch_bounds__(256) void gemm_kernel(const float* __restrict__ x,
                                                   const float* __restrict__ W,
                                                   const float* __restrict__ dinv,
                                                   unsigned int* __restrict__ G) {
  __shared__ float lx[64 * IN_DIM];   // 32 KB
  __shared__ float lw[32 * HID_DIM];  // 16 KB
  const int t = threadIdx.x;
  const int row0 = blockIdx.x * 64;
  const int nrow = min(64, N_NODES - row0);

  {
    const float4* x4 = (const float4*)(x + (size_t)row0 * IN_DIM);
    float4* lx4 = (float4*)lx;
    const int tot = nrow * (IN_DIM / 4);
    for (int i = t; i < tot; i += 256) lx4[i] = x4[i];
  }

  const int c0 = (t & 31) * 4;        // 4 output cols
  const int rbase = (t >> 5) * 8;     // 8 output rows
  float4 acc[8];
#pragma unroll
  for (int i = 0; i < 8; i++) acc[i] = make_float4(0.f, 0.f, 0.f, 0.f);

  for (int kc = 0; kc < IN_DIM; kc += 32) {
    __syncthreads();
    {
      const float4* W4 = (const float4*)(W + (size_t)kc * HID_DIM);
      float4* lw4 = (float4*)lw;
      for (int i = t; i < 32 * HID_DIM / 4; i += 256) lw4[i] = W4[i];
    }
    __syncthreads();
#pragma unroll
    for (int kk = 0; kk < 32; kk += 4) {
      float4 xv[8];
#pragma unroll
      for (int i = 0; i < 8; i++)
        xv[i] = *(const float4*)&lx[(rbase + i) * IN_DIM + kc + kk];
#pragma unroll
      for (int j = 0; j < 4; j++) {
        float4 wv = *(const float4*)&lw[(kk + j) * HID_DIM + c0];
#pragma unroll
        for (int i = 0; i < 8; i++) {
          float xs = (j == 0) ? xv[i].x : (j == 1) ? xv[i].y : (j == 2) ? xv[i].z : xv[i].w;
          acc[i].x += xs * wv.x;
          acc[i].y += xs * wv.y;
          acc[i].z += xs * wv.z;
          acc[i].w += xs * wv.w;
        }
      }
    }
  }
#pragma unroll
  for (int i = 0; i < 8; i++) {
    int r = row0 + rbase + i;
    if (r < N_NODES) {
      float d = dinv[r];
      float4 v = acc[i];
      int pk = __builtin_amdgcn_cvt_pk_fp8_f32(v.x * d, v.y * d, 0, false);
      pk = __builtin_amdgcn_cvt_pk_fp8_f32(v.z * d, v.w * d, pk, true);
      G[(size_t)r * (HID_DIM / 4) + (c0 >> 2)] = (unsigned int)pk;
    }
  }
}

// ---------- per-node gather-sum (fp8 G), 2 edges per wave-load ----------
// lanes 0-31 cover edge i (4 fp8 cols per lane); lanes 32-63 cover edge i+1.
__global__ __launch_bounds__(256) void aggregate_kernel(
    const unsigned int* __restrict__ G, const int* __restrict__ rowptr,
    const int* __restrict__ csr, const float* __restrict__ dinv,
    const float* __restrict__ wacc, const float* __restrict__ b1,
    float* __restrict__ S) {
  const int lane = threadIdx.x & 63;
  const int sub = lane & 31;   // column group: cols [4*sub, 4*sub+4)
  const int half = lane >> 5;  // which edge of the pair
  const int wid = blockIdx.x * (blockDim.x >> 6) + (threadIdx.x >> 6);
  const int nwaves = gridDim.x * (blockDim.x >> 6);
  const float4 b = ((const float4*)b1)[sub];
  v2f sacc01 = {0.f, 0.f}, sacc23 = {0.f, 0.f};

  for (int c = wid; c < N_NODES; c += nwaves) {
    const int start = rowptr[c];
    const int cnum = rowptr[c + 1] - start;
    v2f a01 = {0.f, 0.f}, a23 = {0.f, 0.f};
    if (half == 0) {  // self loop counted once
      unsigned int g = G[c * 32 + sub];
      a01 = __builtin_amdgcn_cvt_pk_f32_fp8((int)g, false);
      a23 = __builtin_amdgcn_cvt_pk_f32_fp8((int)g, true);
    }
    for (int j0 = 0; j0 < cnum; j0 += 64) {
      int src = 0;
      if (j0 + lane < cnum) src = csr[start + j0 + lane];
      const int m = min(64, cnum - j0);
      int i = 0;
      for (; i + 8 <= m; i += 8) {
        int s0 = __shfl(src, i + half);
        int s1 = __shfl(src, i + 2 + half);
        int s2 = __shfl(src, i + 4 + half);
        int s3 = __shfl(src, i + 6 + half);
        unsigned int g0 = G[s0 * 32 + sub];
        unsigned int g1 = G[s1 * 32 + sub];
        unsigned int g2 = G[s2 * 32 + sub];
        unsigned int g3 = G[s3 * 32 + sub];
        a01 += __builtin_amdgcn_cvt_pk_f32_fp8((int)g0, false) +
               __builtin_amdgcn_cvt_pk_f32_fp8((int)g1, false);
        a23 += __builtin_amdgcn_cvt_pk_f32_fp8((int)g0, true) +
               __builtin_amdgcn_cvt_pk_f32_fp8((int)g1, true);
        a01 += __builtin_amdgcn_cvt_pk_f32_fp8((int)g2, false) +
               __builtin_amdgcn_cvt_pk_f32_fp8((int)g3, false);
        a23 += __builtin_amdgcn_cvt_pk_f32_fp8((int)g2, true) +
               __builtin_amdgcn_cvt_pk_f32_fp8((int)g3, true);
      }
      for (; i + 2 <= m; i += 2) {
        int s = __shfl(src, i + half);
        unsigned int g = G[s * 32 + sub];
        a01 += __builtin_amdgcn_cvt_pk_f32_fp8((int)g, false);
        a23 += __builtin_amdgcn_cvt_pk_f32_fp8((int)g, true);
      }
      if (i < m) {  // odd leftover edge: lanes 0-31 only
        int s = __shfl(src, i);
        if (half == 0) {
          unsigned int g = G[s * 32 + sub];
          a01 += __builtin_amdgcn_cvt_pk_f32_fp8((int)g, false);
          a23 += __builtin_amdgcn_cvt_pk_f32_fp8((int)g, true);
        }
      }
    }
    // merge upper-half partial sums into lanes 0-31
    a01.x += __shfl(a01.x, sub + 32);
    a01.y += __shfl(a01.y, sub + 32);
    a23.x += __shfl(a23.x, sub + 32);
    a23.y += __shfl(a23.y, sub + 32);
    if (half == 0) {
      float d = dinv[c];
      float wc = d * (wacc[c] + d);  // layer-2 weight
      sacc01.x += wc * fmaxf(fmaf(d, a01.x, b.x), 0.f);
      sacc01.y += wc * fmaxf(fmaf(d, a01.y, b.y), 0.f);
      sacc23.x += wc * fmaxf(fmaf(d, a23.x, b.z), 0.f);
      sacc23.y += wc * fmaxf(fmaf(d, a23.y, b.w), 0.f);
    }
  }

  __shared__ float ls[HID_DIM];
  if (threadIdx.x < HID_DIM) ls[threadIdx.x] = 0.f;
  __syncthreads();
  if (half == 0) {
    atomicAdd(&ls[4 * sub + 0], sacc01.x);
    atomicAdd(&ls[4 * sub + 1], sacc01.y);
    atomicAdd(&ls[4 * sub + 2], sacc23.x);
    atomicAdd(&ls[4 * sub + 3], sacc23.y);
  }
  __syncthreads();
  if (threadIdx.x < HID_DIM) atomicAdd(&S[threadIdx.x], ls[threadIdx.x]);
}

// ---------- out[j] = (1/N) * S @ W2 + b2 ----------
__global__ void finish_kernel(const float* __restrict__ S, const float* __restrict__ W2,
                              const float* __restrict__ b2, float* __restrict__ out) {
  int j = threadIdx.x;  // 64
  float acc = 0.f;
  for (int k = 0; k < HID_DIM; k++) acc += S[k] * W2[k * OUT_DIM + j];
  out[j] = acc * (1.0f / N_NODES) + b2[j];
}

extern "C" void kernel_launch(void* const* d_in, const int* in_sizes, int n_in,
                              void* d_out, int out_size, void* d_ws, size_t ws_size,
                              hipStream_t stream) {
  const float* x  = (const float*)d_in[0];
  const void*  ei = d_in[1];
  const float* W1 = (const float*)d_in[2];
  const float* b1 = (const float*)d_in[3];
  const float* W2 = (const float*)d_in[4];
  const float* b2 = (const float*)d_in[5];
  float* out = (float*)d_out;

  char* p = (char*)d_ws;
  size_t off = 0;
  auto alloc = [&](size_t bytes) -> void* {
    void* r = p + off;
    off = (off + bytes + 63) & ~(size_t)63;
    return r;
  };
  int*   flag   = (int*)alloc(64);
  int*   hist   = (int*)alloc((size_t)HIST_N2 * 4);                // 800 KB
  int*   bsum   = (int*)alloc(1024 * 4);
  unsigned int* pairs = (unsigned int*)alloc((size_t)2 * N_EDGES * 4);  // 12.8 MB
  int*   rowptr = (int*)alloc(((size_t)N_NODES + 1) * 4);
  int*   csr    = (int*)alloc((size_t)N_EDGES * 4);                // 6.4 MB
  float* dinv   = (float*)alloc((size_t)N_NODES * 4);
  float* wacc   = (float*)alloc((size_t)N_NODES * 4);
  float* S      = (float*)alloc(HID_DIM * 4);
  unsigned int* G = (unsigned int*)alloc((size_t)N_NODES * HID_DIM);  // 12.8 MB fp8
  (void)ws_size; (void)n_in; (void)in_sizes; (void)out_size;

  const int NBH = HIST_N2 / 256;  // 782, exact

  detect_kernel<<<1, 256, 0, stream>>>((const unsigned int*)ei, flag, S);
  hist_kernel<<<B1, 256, 0, stream>>>(ei, flag, hist);
  scan1_kernel<<<NBH, 256, 0, stream>>>(hist, hist, bsum, HIST_N2);
  scan2_kernel<<<1, 1024, 0, stream>>>(bsum, NBH);
  scan3_kernel<<<NBH, 256, 0, stream>>>(hist, bsum, HIST_N2);
  scatter_kernel<<<B1, 256, 0, stream>>>(ei, flag, hist, pairs);
  csr_kernel<<<NBKT, 256, 0, stream>>>(hist, pairs, rowptr, csr, dinv);
  outsum_kernel<<<NBKT, 256, 0, stream>>>(hist, pairs, dinv, wacc);
  gemm_kernel<<<(N_NODES + 63) / 64, 256, 0, stream>>>(x, W1, dinv, G);
  aggregate_kernel<<<2048, 256, 0, stream>>>(G, rowptr, csr, dinv, wacc, b1, S);
  finish_kernel<<<1, 64, 0, stream>>>(S, W2, b2, out);
}